// Round 1
// baseline (34504.556 us; speedup 1.0000x reference)
//
#include <hip/hip_runtime.h>

typedef unsigned short u16;
typedef short short8 __attribute__((ext_vector_type(8)));
typedef __bf16 bf16x8 __attribute__((ext_vector_type(8)));
typedef float f32x4 __attribute__((ext_vector_type(4)));

#define DEV static __device__ __forceinline__

// ---------------------------------------------------------------- params
struct Params {
  const float *x, *eps;
  const float *Wih_ef, *Whh_ef, *bih_ef, *bhh_ef;
  const float *Wih_eb, *Whh_eb, *bih_eb, *bhh_eb;
  const float *W_mu0, *b_mu0, *W_lv0, *b_lv0;
  const float *Wih_c, *Whh_c, *bih_c, *bhh_c;
  const float *W_cmu, *b_cmu, *W_clv, *b_clv;
  const float *Wih_g, *Whh_g, *bih_g, *bhh_g;
  const float *W_f, *b_f, *W_r, *b_r;
  // workspace (bf16 weights / staged x)
  u16 *Xbf;                                   // [T][B][D] bf16
  u16 *wihef, *whhef, *wiheb, *whheb;
  u16 *wihc, *whhc, *wihg, *whhg;
  u16 *wmu0, *wlv0, *wcmu, *wclv, *wf, *wr;
  // recurrent state (f32 master + bf16 mirror), double buffered by parity
  float *ehf32;   // [2 dir][2 par][256*256]
  float *chf32;   // [2 par][256*256]
  float *ghf32;   // [2 par][256*256]
  float *Fbuf;    // [256][64] previous factors (f32)
  u16   *ehbf, *chbf, *ghbf;
  float *klacc;   // [16] ctrl-KL partial per block
  float *klics;   // [16] ic-KL partial per block
  float *out;
};

constexpr size_t RATES_N = 33554432ull;       // 256*512*256
constexpr size_t FOUT    = RATES_N + 2ull;    // factors_all offset in d_out

// ---------------------------------------------------------------- helpers
DEV u16 f2bf(float x) {
  unsigned u = __builtin_bit_cast(unsigned, x);
  u = (u + 0x7FFFu + ((u >> 16) & 1u)) >> 16;   // RNE
  return (u16)u;
}
DEV f32x4 MFMA(short8 a, short8 b, f32x4 c) {
  return __builtin_amdgcn_mfma_f32_16x16x32_bf16(
      __builtin_bit_cast(bf16x8, a), __builtin_bit_cast(bf16x8, b), c, 0, 0, 0);
}
// A/B fragment: lane = row/col (lane&15), k = (lane>>4)*8 + e (contiguous 16B)
DEV short8 ldfrag(const u16* p0, int stride) {
  const int l = threadIdx.x & 63;
  const u16* p = p0 + (size_t)(l & 15) * stride + ((l >> 4) << 3);
  return *reinterpret_cast<const short8*>(p);
}
DEV short8 ldfrag_f32(const float* p0, int stride) {
  const int l = threadIdx.x & 63;
  const float* p = p0 + (size_t)(l & 15) * stride + ((l >> 4) << 3);
  f32x4 a = *reinterpret_cast<const f32x4*>(p);
  f32x4 b = *reinterpret_cast<const f32x4*>(p + 4);
  short8 r;
  r[0]=(short)f2bf(a[0]); r[1]=(short)f2bf(a[1]); r[2]=(short)f2bf(a[2]); r[3]=(short)f2bf(a[3]);
  r[4]=(short)f2bf(b[0]); r[5]=(short)f2bf(b[1]); r[6]=(short)f2bf(b[2]); r[7]=(short)f2bf(b[3]);
  return r;
}
DEV float sigm(float x) { return 1.f / (1.f + __expf(-x)); }

DEV void cvtarr(const float* s, u16* d, size_t n, size_t g, size_t gs) {
  for (size_t i = g; i < n; i += gs) d[i] = f2bf(s[i]);
}
DEV void zf(float* d, size_t n, size_t g, size_t gs) {
  for (size_t i = g; i < n; i += gs) d[i] = 0.f;
}
DEV void zu(u16* d, size_t n, size_t g, size_t gs) {
  for (size_t i = g; i < n; i += gs) d[i] = 0;
}

// ---------------------------------------------------------------- init
__global__ __launch_bounds__(256) void k_init(Params P) {
  const size_t g  = (size_t)blockIdx.x * 256 + threadIdx.x;
  const size_t gs = (size_t)gridDim.x * 256;
  // x [B,T,D] f32 -> Xbf [T,B,D] bf16
  for (size_t i = g; i < 4194304ull; i += gs) {
    size_t flat = i << 3;
    int b = (int)(flat >> 17);
    int rem = (int)(flat & 131071);
    int t = rem >> 8, d = rem & 255;
    const float* s = P.x + flat;
    f32x4 v0 = *(const f32x4*)s, v1 = *(const f32x4*)(s + 4);
    short8 o;
    o[0]=(short)f2bf(v0[0]); o[1]=(short)f2bf(v0[1]); o[2]=(short)f2bf(v0[2]); o[3]=(short)f2bf(v0[3]);
    o[4]=(short)f2bf(v1[0]); o[5]=(short)f2bf(v1[1]); o[6]=(short)f2bf(v1[2]); o[7]=(short)f2bf(v1[3]);
    *reinterpret_cast<short8*>(P.Xbf + (((size_t)t * 256 + b) << 8) + d) = o;
  }
  cvtarr(P.Wih_ef, P.wihef, 196608, g, gs);
  cvtarr(P.Whh_ef, P.whhef, 196608, g, gs);
  cvtarr(P.Wih_eb, P.wiheb, 196608, g, gs);
  cvtarr(P.Whh_eb, P.whheb, 196608, g, gs);
  cvtarr(P.Wih_c,  P.wihc,  245760, g, gs);
  cvtarr(P.Whh_c,  P.whhc,  196608, g, gs);
  cvtarr(P.Wih_g,  P.wihg,   49152, g, gs);
  cvtarr(P.Whh_g,  P.whhg,  196608, g, gs);
  cvtarr(P.W_mu0,  P.wmu0,   32768, g, gs);
  cvtarr(P.W_lv0,  P.wlv0,   32768, g, gs);
  cvtarr(P.W_cmu,  P.wcmu,   16384, g, gs);
  cvtarr(P.W_clv,  P.wclv,   16384, g, gs);
  cvtarr(P.W_f,    P.wf,     16384, g, gs);
  cvtarr(P.W_r,    P.wr,     16384, g, gs);
  // zero initial states (h0/c0/g0/f0 = 0) -- must happen EVERY call
  zf(P.ehf32, 262144, g, gs);  zu(P.ehbf, 262144, g, gs);
  zf(P.chf32, 131072, g, gs);  zu(P.chbf, 131072, g, gs);
  zf(P.ghf32, 131072, g, gs);  zu(P.ghbf, 131072, g, gs);
  zf(P.Fbuf,   16384, g, gs);
}

// ---------------------------------------------------------------- main recurrent kernel
// grid: 48 blocks x 1024 threads.  blocks 0..15: ctrl+gen (batch rows 16*blk..+16)
// blocks 16..47: encoder (dir = (blk-16)>>4, rows = ((blk-16)&15)*16)
DEV void cg_role(const Params& P, int blk, float* sml, float* sred) {
  const int lane = threadIdx.x & 63, wid = threadIdx.x >> 6;  // 16 waves
  const int cl = lane & 15, rq = (lane >> 4) << 2;
  const int b0 = blk << 4;
  const int j0 = wid << 4;
  const u16* Wi0 = P.wihc + (size_t)j0 * 320;
  const u16* Wh0 = P.whhc + (size_t)j0 * 256;
  const u16* Wgh0 = P.whhg + (size_t)j0 * 256;
  const u16* Wgi0 = P.wihg + (size_t)j0 * 64;
  float klsum = 0.f;

#pragma unroll 1
  for (int t = 0; t < 512; ++t) {
    const int cur = t & 1, prv = cur ^ 1;
    // ================= P1: controller GRU step =================
    {
      f32x4 ar = {0,0,0,0}, az = {0,0,0,0}, agn = {0,0,0,0}, ahn = {0,0,0,0};
      const u16* Ax  = P.Xbf  + (((size_t)t * 256 + b0) << 8);
      const u16* Ahc = P.chbf + (size_t)prv * 65536 + ((size_t)b0 << 8);
      const float* Af = P.Fbuf + b0 * 64;
#pragma unroll
      for (int kk = 0; kk < 8; ++kk) {
        short8 A = ldfrag(Ax + kk * 32, 256);
        short8 H = ldfrag(Ahc + kk * 32, 256);
        ar  = MFMA(A, ldfrag(Wi0 + kk * 32, 320), ar);
        az  = MFMA(A, ldfrag(Wi0 + 256 * 320 + kk * 32, 320), az);
        agn = MFMA(A, ldfrag(Wi0 + 512 * 320 + kk * 32, 320), agn);
        ar  = MFMA(H, ldfrag(Wh0 + kk * 32, 256), ar);
        az  = MFMA(H, ldfrag(Wh0 + 256 * 256 + kk * 32, 256), az);
        ahn = MFMA(H, ldfrag(Wh0 + 512 * 256 + kk * 32, 256), ahn);
      }
#pragma unroll
      for (int kk = 0; kk < 2; ++kk) {      // prev-factors slice of c_in (cols 256..319)
        short8 A = ldfrag_f32(Af + kk * 32, 64);
        ar  = MFMA(A, ldfrag(Wi0 + 256 + kk * 32, 320), ar);
        az  = MFMA(A, ldfrag(Wi0 + 256 * 320 + 256 + kk * 32, 320), az);
        agn = MFMA(A, ldfrag(Wi0 + 512 * 320 + 256 + kk * 32, 320), agn);
      }
      const int j = j0 + cl;
#pragma unroll
      for (int q = 0; q < 4; ++q) {
        const int b = b0 + rq + q;
        float r = sigm(ar[q] + P.bih_c[j] + P.bhh_c[j]);
        float z = sigm(az[q] + P.bih_c[256 + j] + P.bhh_c[256 + j]);
        float n = tanhf(agn[q] + P.bih_c[512 + j] + r * (ahn[q] + P.bhh_c[512 + j]));
        float hp = P.chf32[(size_t)prv * 65536 + (b << 8) + j];
        float h = (1.f - z) * n + z * hp;
        P.chf32[(size_t)cur * 65536 + (b << 8) + j] = h;
        P.chbf [(size_t)cur * 65536 + (b << 8) + j] = f2bf(h);
      }
    }
    __syncthreads();
    // ================= P2a: mu_u / lv_u heads =================
    if (wid < 8) {
      const int sel = wid >> 2, l0 = (wid & 3) << 4;
      const u16* Wm = (sel ? P.wclv : P.wcmu) + (size_t)l0 * 256;
      const float* bm = sel ? P.b_clv : P.b_cmu;
      const u16* Ac = P.chbf + (size_t)cur * 65536 + ((size_t)b0 << 8);
      f32x4 am = {0,0,0,0};
#pragma unroll
      for (int kk = 0; kk < 8; ++kk)
        am = MFMA(ldfrag(Ac + kk * 32, 256), ldfrag(Wm + kk * 32, 256), am);
#pragma unroll
      for (int q = 0; q < 4; ++q)
        sml[(rq + q) * 132 + sel * 64 + l0 + cl] = am[q] + bm[l0 + cl];
    }
    __syncthreads();
    // ================= P2b: u_t + generator GRU step =================
    {
      short8 U[2];
#pragma unroll
      for (int kk = 0; kk < 2; ++kk) {
        const int kb = kk * 32 + ((lane >> 4) << 3);
        const float* ep = P.eps + ((size_t)t * 256 + b0 + cl) * 64 + kb;
        f32x4 e0 = *(const f32x4*)ep;
        f32x4 e1 = *(const f32x4*)(ep + 4);
        short8 uu;
#pragma unroll
        for (int j2 = 0; j2 < 8; ++j2) {
          float mu = sml[cl * 132 + kb + j2];
          float lv = sml[cl * 132 + 64 + kb + j2];
          float e = (j2 < 4) ? e0[j2] : e1[j2 - 4];
          uu[j2] = (short)f2bf(mu + e * __expf(0.5f * lv));
        }
        U[kk] = uu;
      }
      f32x4 gr = {0,0,0,0}, gz = {0,0,0,0}, ggn = {0,0,0,0}, ghn = {0,0,0,0};
      const u16* Agh = P.ghbf + (size_t)prv * 65536 + ((size_t)b0 << 8);
#pragma unroll
      for (int kk = 0; kk < 8; ++kk) {
        short8 A = ldfrag(Agh + kk * 32, 256);
        gr  = MFMA(A, ldfrag(Wgh0 + kk * 32, 256), gr);
        gz  = MFMA(A, ldfrag(Wgh0 + 256 * 256 + kk * 32, 256), gz);
        ghn = MFMA(A, ldfrag(Wgh0 + 512 * 256 + kk * 32, 256), ghn);
      }
#pragma unroll
      for (int kk = 0; kk < 2; ++kk) {
        gr  = MFMA(U[kk], ldfrag(Wgi0 + kk * 32, 64), gr);
        gz  = MFMA(U[kk], ldfrag(Wgi0 + 256 * 64 + kk * 32, 64), gz);
        ggn = MFMA(U[kk], ldfrag(Wgi0 + 512 * 64 + kk * 32, 64), ggn);
      }
      const int j = j0 + cl;
#pragma unroll
      for (int q = 0; q < 4; ++q) {
        const int b = b0 + rq + q;
        float r = sigm(gr[q] + P.bih_g[j] + P.bhh_g[j]);
        float z = sigm(gz[q] + P.bih_g[256 + j] + P.bhh_g[256 + j]);
        float n = tanhf(ggn[q] + P.bih_g[512 + j] + r * (ghn[q] + P.bhh_g[512 + j]));
        float hp = P.ghf32[(size_t)prv * 65536 + (b << 8) + j];
        float h = (1.f - z) * n + z * hp;
        P.ghf32[(size_t)cur * 65536 + (b << 8) + j] = h;
        P.ghbf [(size_t)cur * 65536 + (b << 8) + j] = f2bf(h);
      }
    }
    __syncthreads();
    // ================= P3: factors + KL partial =================
    if (wid < 4) {
      const int l0 = wid << 4;
      const u16* Ag = P.ghbf + (size_t)cur * 65536 + ((size_t)b0 << 8);
      const u16* Wf = P.wf + (size_t)l0 * 256;
      f32x4 af = {0,0,0,0};
#pragma unroll
      for (int kk = 0; kk < 8; ++kk)
        af = MFMA(ldfrag(Ag + kk * 32, 256), ldfrag(Wf + kk * 32, 256), af);
#pragma unroll
      for (int q = 0; q < 4; ++q) {
        const int b = b0 + rq + q;
        float f = af[q] + P.b_f[l0 + cl];
        P.Fbuf[b * 64 + l0 + cl] = f;
        P.out[FOUT + (size_t)b * 32768 + (size_t)t * 64 + l0 + cl] = f;
      }
    }
    {
      const int rr = threadIdx.x >> 6, cc = threadIdx.x & 63;
      float mu = sml[rr * 132 + cc], lv = sml[rr * 132 + 64 + cc];
      float v = __expf(lv) + mu * mu - 1.f - lv;
      v += __shfl_down(v, 32); v += __shfl_down(v, 16); v += __shfl_down(v, 8);
      v += __shfl_down(v, 4);  v += __shfl_down(v, 2);  v += __shfl_down(v, 1);
      if (lane == 0) sred[wid] = v;
    }
    __syncthreads();   // makes Fbuf + sred visible; separates sml reads from next P2a
    if (threadIdx.x == 0) {
      float s = 0.f;
#pragma unroll
      for (int i2 = 0; i2 < 16; ++i2) s += sred[i2];
      klsum += s;
    }
  }
  if (threadIdx.x == 0) P.klacc[blk] = klsum;
}

DEV void enc_role(const Params& P, int dir, int b0) {
  const int lane = threadIdx.x & 63, wid = threadIdx.x >> 6;
  const int cl = lane & 15, rq = (lane >> 4) << 2;
  const int j0 = wid << 4;
  const u16* Wih = dir ? P.wiheb : P.wihef;
  const u16* Whh = dir ? P.whheb : P.whhef;
  const float* bih = dir ? P.bih_eb : P.bih_ef;
  const float* bhh = dir ? P.bhh_eb : P.bhh_ef;
  float* hf = P.ehf32 + (size_t)dir * 131072;
  u16*   hb = P.ehbf  + (size_t)dir * 131072;
  const u16* Wi0 = Wih + (size_t)j0 * 256;
  const u16* Wh0 = Whh + (size_t)j0 * 256;
#pragma unroll 1
  for (int i = 0; i < 512; ++i) {
    const int cur = i & 1, prv = cur ^ 1;
    const int t = dir ? (511 - i) : i;
    const u16* Ax = P.Xbf + (((size_t)t * 256 + b0) << 8);
    const u16* Ah = hb + (size_t)prv * 65536 + ((size_t)b0 << 8);
    f32x4 ar = {0,0,0,0}, az = {0,0,0,0}, agn = {0,0,0,0}, ahn = {0,0,0,0};
#pragma unroll
    for (int kk = 0; kk < 8; ++kk) {
      short8 A = ldfrag(Ax + kk * 32, 256);
      short8 H = ldfrag(Ah + kk * 32, 256);
      ar  = MFMA(A, ldfrag(Wi0 + kk * 32, 256), ar);
      az  = MFMA(A, ldfrag(Wi0 + 256 * 256 + kk * 32, 256), az);
      agn = MFMA(A, ldfrag(Wi0 + 512 * 256 + kk * 32, 256), agn);
      ar  = MFMA(H, ldfrag(Wh0 + kk * 32, 256), ar);
      az  = MFMA(H, ldfrag(Wh0 + 256 * 256 + kk * 32, 256), az);
      ahn = MFMA(H, ldfrag(Wh0 + 512 * 256 + kk * 32, 256), ahn);
    }
    const int j = j0 + cl;
#pragma unroll
    for (int q = 0; q < 4; ++q) {
      const int b = b0 + rq + q;
      float r = sigm(ar[q] + bih[j] + bhh[j]);
      float z = sigm(az[q] + bih[256 + j] + bhh[256 + j]);
      float n = tanhf(agn[q] + bih[512 + j] + r * (ahn[q] + bhh[512 + j]));
      float hp = hf[(size_t)prv * 65536 + (b << 8) + j];
      float h = (1.f - z) * n + z * hp;
      hf[(size_t)cur * 65536 + (b << 8) + j] = h;
      hb[(size_t)cur * 65536 + (b << 8) + j] = f2bf(h);
    }
    __syncthreads();
  }
}

__global__ __launch_bounds__(1024) void k_main(Params P) {
  __shared__ float sml[16 * 132];
  __shared__ float sred[16];
  const int blk = blockIdx.x;
  if (blk < 16) cg_role(P, blk, sml, sred);
  else {
    const int e = blk - 16;
    enc_role(P, e >> 4, (e & 15) << 4);
  }
}

// ---------------------------------------------------------------- post: IC heads + rates
__global__ __launch_bounds__(256) void k_post(Params P) {
  __shared__ float sml[16 * 132];
  __shared__ float sred[4];
  const int lane = threadIdx.x & 63, wid = threadIdx.x >> 6;
  const int cl = lane & 15, rq = (lane >> 4) << 2;
  const int blk = blockIdx.x;
  if (blk < 16) {
    // mu0/lv0 = h_enc @ W.T + b ; h_enc = [h_fwd_final | h_bwd_final] (parity 1)
    const int b0 = blk << 4;
    const u16* Af = P.ehbf + 65536 + ((size_t)b0 << 8);
    const u16* Ab = P.ehbf + 131072 + 65536 + ((size_t)b0 << 8);
    const int l0 = wid << 4;
#pragma unroll
    for (int sel = 0; sel < 2; ++sel) {
      const u16* W = (sel ? P.wlv0 : P.wmu0) + (size_t)l0 * 512;
      const float* bb = sel ? P.b_lv0 : P.b_mu0;
      f32x4 a = {0,0,0,0};
#pragma unroll
      for (int kk = 0; kk < 8; ++kk) {
        a = MFMA(ldfrag(Af + kk * 32, 256), ldfrag(W + kk * 32, 512), a);
        a = MFMA(ldfrag(Ab + kk * 32, 256), ldfrag(W + 256 + kk * 32, 512), a);
      }
#pragma unroll
      for (int q = 0; q < 4; ++q)
        sml[(rq + q) * 132 + sel * 64 + l0 + cl] = a[q] + bb[l0 + cl];
    }
    __syncthreads();
    float v = 0.f;
    for (int idx = threadIdx.x; idx < 1024; idx += 256) {
      int rr = idx >> 6, cc = idx & 63;
      float mu = sml[rr * 132 + cc], lv = sml[rr * 132 + 64 + cc];
      v += __expf(lv) + mu * mu - 1.f - lv;
    }
    v += __shfl_down(v, 32); v += __shfl_down(v, 16); v += __shfl_down(v, 8);
    v += __shfl_down(v, 4);  v += __shfl_down(v, 2);  v += __shfl_down(v, 1);
    if (lane == 0) sred[wid] = v;
    __syncthreads();
    if (threadIdx.x == 0) P.klics[blk] = sred[0] + sred[1] + sred[2] + sred[3];
  } else {
    // rates[b,t,:] = exp(factors[b,t,:] @ W_r.T + b_r)
    const int gw = (blk - 16) * 4 + wid;
    const size_t r0 = (size_t)gw << 4;
    const float* Fs = P.out + FOUT;
    short8 A0 = ldfrag_f32(Fs + r0 * 64, 64);
    short8 A1 = ldfrag_f32(Fs + r0 * 64 + 32, 64);
#pragma unroll 1
    for (int ct = 0; ct < 16; ++ct) {
      const int d0 = ct << 4;
      const u16* W = P.wr + (size_t)d0 * 64;
      f32x4 a = {0,0,0,0};
      a = MFMA(A0, ldfrag(W, 64), a);
      a = MFMA(A1, ldfrag(W + 32, 64), a);
#pragma unroll
      for (int q = 0; q < 4; ++q) {
        const size_t row = r0 + rq + q;
        P.out[row * 256 + d0 + cl] = __expf(a[q] + P.b_r[d0 + cl]);
      }
    }
  }
}

__global__ void k_final(Params P) {
  if (threadIdx.x == 0) {
    float s = 0.f, s2 = 0.f;
    for (int i = 0; i < 16; ++i) { s += P.klacc[i]; s2 += P.klics[i]; }
    P.out[RATES_N]     = s2 * (0.5f / 256.f);            // kl_ics
    P.out[RATES_N + 1] = s  * (0.5f / (256.f * 512.f));  // kl_ctrl
  }
}

// ---------------------------------------------------------------- launch
extern "C" void kernel_launch(void* const* d_in, const int* in_sizes, int n_in,
                              void* d_out, int out_size, void* d_ws, size_t ws_size,
                              hipStream_t stream) {
  (void)in_sizes; (void)n_in; (void)out_size; (void)ws_size;
  Params P;
  const float* const* in = (const float* const*)d_in;
  P.x = in[0];      P.eps = in[1];
  P.Wih_ef = in[2]; P.Whh_ef = in[3]; P.bih_ef = in[4]; P.bhh_ef = in[5];
  P.Wih_eb = in[6]; P.Whh_eb = in[7]; P.bih_eb = in[8]; P.bhh_eb = in[9];
  P.W_mu0 = in[10]; P.b_mu0 = in[11]; P.W_lv0 = in[12]; P.b_lv0 = in[13];
  P.Wih_c = in[14]; P.Whh_c = in[15]; P.bih_c = in[16]; P.bhh_c = in[17];
  P.W_cmu = in[18]; P.b_cmu = in[19]; P.W_clv = in[20]; P.b_clv = in[21];
  P.Wih_g = in[22]; P.Whh_g = in[23]; P.bih_g = in[24]; P.bhh_g = in[25];
  P.W_f = in[26];   P.b_f = in[27];   P.W_r = in[28];   P.b_r = in[29];

  char* w = (char*)d_ws;
  size_t off = 0;
  auto take = [&](size_t bytes) -> char* {
    char* r = w + off;
    off = (off + bytes + 255) & ~(size_t)255;
    return r;
  };
  P.Xbf   = (u16*)take(33554432ull * 2);
  P.wihef = (u16*)take(196608ull * 2);
  P.whhef = (u16*)take(196608ull * 2);
  P.wiheb = (u16*)take(196608ull * 2);
  P.whheb = (u16*)take(196608ull * 2);
  P.wihc  = (u16*)take(245760ull * 2);
  P.whhc  = (u16*)take(196608ull * 2);
  P.wihg  = (u16*)take(49152ull * 2);
  P.whhg  = (u16*)take(196608ull * 2);
  P.wmu0  = (u16*)take(32768ull * 2);
  P.wlv0  = (u16*)take(32768ull * 2);
  P.wcmu  = (u16*)take(16384ull * 2);
  P.wclv  = (u16*)take(16384ull * 2);
  P.wf    = (u16*)take(16384ull * 2);
  P.wr    = (u16*)take(16384ull * 2);
  P.ehf32 = (float*)take(262144ull * 4);
  P.chf32 = (float*)take(131072ull * 4);
  P.ghf32 = (float*)take(131072ull * 4);
  P.Fbuf  = (float*)take(16384ull * 4);
  P.ehbf  = (u16*)take(262144ull * 2);
  P.chbf  = (u16*)take(131072ull * 2);
  P.ghbf  = (u16*)take(131072ull * 2);
  P.klacc = (float*)take(16ull * 4);
  P.klics = (float*)take(16ull * 4);
  P.out = (float*)d_out;

  hipLaunchKernelGGL(k_init,  dim3(1024), dim3(256),  0, stream, P);
  hipLaunchKernelGGL(k_main,  dim3(48),   dim3(1024), 0, stream, P);
  hipLaunchKernelGGL(k_post,  dim3(2064), dim3(256),  0, stream, P);
  hipLaunchKernelGGL(k_final, dim3(1),    dim3(64),   0, stream, P);
}

// Round 2
// 7184.288 us; speedup vs baseline: 4.8028x; 4.8028x over previous
//
#include <hip/hip_runtime.h>

typedef unsigned char u8;
typedef unsigned short u16;
typedef unsigned long long u64;
typedef short short8 __attribute__((ext_vector_type(8)));
typedef __bf16 bf16x8 __attribute__((ext_vector_type(8)));
typedef float f32x4 __attribute__((ext_vector_type(4)));

#define DEV static __device__ __forceinline__

// ---------------------------------------------------------------- params
struct Params {
  const float *x, *eps;
  const float *Wih_ef, *Whh_ef, *bih_ef, *bhh_ef;
  const float *Wih_eb, *Whh_eb, *bih_eb, *bhh_eb;
  const float *W_mu0, *b_mu0, *W_lv0, *b_lv0;
  const float *Wih_c, *Whh_c, *bih_c, *bhh_c;
  const float *W_cmu, *b_cmu, *W_clv, *b_clv;
  const float *Wih_g, *Whh_g, *bih_g, *bhh_g;
  const float *W_f, *b_f, *W_r, *b_r;
  // workspace
  u8  *Xf8;                 // [T][B][256] fp8
  u16 *Xbf2;                // [T][B][256] bf16 (for k_gx)
  u16 *wihcbf;              // [768][256] bf16 (ctrl x-part, k_gx A)
  float *bfc;               // [768] fused bias for Gxc
  u8 *wihef8, *whhef8, *wiheb8, *whheb8;    // enc fp8 [768][256]
  u8 *whhc8, *whhg8;                        // cg fp8 [768][256]
  u8 *wihcf8, *wihg8;                       // fp8 [768][64]
  u8 *wf8;                                  // fp8 [64][256]
  u8 *wcmu8, *wclv8;                        // fp8 [64][256]
  u16 *wrbf;                                // [256][64] bf16 (k_post)
  float *henc;              // [2*256][256] final enc h (f32)
  float *klacc;             // [16]
  float *klics;             // [32]
  u8 *Gxc;                  // [T][768][B] fp8 -> parked in d_out rates region
  float *out;
};

constexpr size_t RATES_N = 33554432ull;       // 256*512*256
constexpr size_t FOUT    = RATES_N + 2ull;    // factors_all offset in d_out

// ---------------------------------------------------------------- scalar helpers
DEV u16 f2bf(float x) {
  unsigned u = __builtin_bit_cast(unsigned, x);
  u = (u + 0x7FFFu + ((u >> 16) & 1u)) >> 16;   // RNE
  return (u16)u;
}
DEV unsigned f2e4m3(float x) {                   // manual OCP e4m3fn (RNE), order-safe
  unsigned u = __builtin_bit_cast(unsigned, x);
  unsigned s = (u >> 24) & 0x80u;
  float ax = __builtin_bit_cast(float, u & 0x7FFFFFFFu);
  if (ax > 448.f) return s | 0x7E;
  if (ax < 0.0009765625f) return s;              // < 2^-10 -> 0
  if (ax < 0.015625f) {                          // subnormal, step 2^-9
    int m = (int)rintf(ax * 512.f);
    if (m >= 8) return s | 0x08;
    return s | (unsigned)m;
  }
  unsigned au = __builtin_bit_cast(unsigned, ax);
  int E = (int)(au >> 23) - 127;
  unsigned m = au & 0x7FFFFFu;
  unsigned r = (m + 0x7FFFFu + ((m >> 20) & 1u)) >> 20;
  if (r >= 8) { r = 0; ++E; if (E > 8) return s | 0x7E; }
  return s | ((unsigned)(E + 7) << 3) | r;
}
DEV float e4m3tof(unsigned b) {
  unsigned s = (b & 0x80u) << 24;
  unsigned e = (b >> 3) & 15u, m = b & 7u;
  float v;
  if (e) v = __builtin_bit_cast(float, ((e + 120u) << 23) | (m << 20));
  else   v = (float)m * 0.001953125f;
  return __builtin_bit_cast(float, __builtin_bit_cast(unsigned, v) | s);
}
DEV unsigned f8pk1(float x) {                    // value-safe single convert
#if __has_builtin(__builtin_amdgcn_cvt_pk_fp8_f32)
  return (unsigned)__builtin_amdgcn_cvt_pk_fp8_f32(x, x, 0, false) & 255u;
#else
  return f2e4m3(x);
#endif
}
DEV float f8tof(unsigned b) {
#if __has_builtin(__builtin_amdgcn_cvt_f32_fp8)
  return __builtin_amdgcn_cvt_f32_fp8((int)(b & 255u), 0);
#else
  return e4m3tof(b & 255u);
#endif
}
DEV float sigm(float x) { return 1.f / (1.f + __expf(-x)); }
DEV float ftanh(float x) { float t = __expf(2.f * x); return 1.f - 2.f / (t + 1.f); }
DEV float gru_h(float pr, float pz, float pin, float phn, float hp) {
  float r = sigm(pr), z = sigm(pz);
  float n = ftanh(pin + r * phn);
  return (1.f - z) * n + z * hp;
}

// ---------------------------------------------------------------- MFMA helpers
DEV f32x4 MFMA(short8 a, short8 b, f32x4 c) {
  return __builtin_amdgcn_mfma_f32_16x16x32_bf16(
      __builtin_bit_cast(bf16x8, a), __builtin_bit_cast(bf16x8, b), c, 0, 0, 0);
}
DEV f32x4 mfma8(long a, long b, f32x4 c) {
  return __builtin_amdgcn_mfma_f32_16x16x32_fp8_fp8(a, b, c, 0, 0, 0);
}
// bf16 fragment readers (global), round-1 proven
DEV short8 ldfrag(const u16* p0, int stride) {
  const int l = threadIdx.x & 63;
  const u16* p = p0 + (size_t)(l & 15) * stride + ((l >> 4) << 3);
  return *reinterpret_cast<const short8*>(p);
}
DEV short8 ldfrag_f32(const float* p0, int stride) {
  const int l = threadIdx.x & 63;
  const float* p = p0 + (size_t)(l & 15) * stride + ((l >> 4) << 3);
  f32x4 a = *reinterpret_cast<const f32x4*>(p);
  f32x4 b = *reinterpret_cast<const f32x4*>(p + 4);
  short8 r;
  r[0]=(short)f2bf(a[0]); r[1]=(short)f2bf(a[1]); r[2]=(short)f2bf(a[2]); r[3]=(short)f2bf(a[3]);
  r[4]=(short)f2bf(b[0]); r[5]=(short)f2bf(b[1]); r[6]=(short)f2bf(b[2]); r[7]=(short)f2bf(b[3]);
  return r;
}
// fp8 fragment readers. k-map: k = kk*32 + (lane>>4)*8 + e (same for A and B -> cancels)
DEV long glbW8(const u8* w, int r0, int kk) {    // global, rowlen 256
  int l = threadIdx.x & 63;
  return *(const long*)(w + (size_t)(r0 + (l & 15)) * 256 + kk * 32 + ((l >> 4) << 3));
}
DEV long ldsA8(const u8* m, int kk) {            // LDS state, rowlen 256, rows=lane&15
  int l = threadIdx.x & 63;
  int row = l & 15;
  int off = row * 256 + kk * 32 + ((l >> 4) << 3);
  off ^= (row & 7) << 3;
  return *(const long*)(m + off);
}
DEV long ldsW8(const u8* m, int r0, int rowlen, int kk) {  // LDS weights
  int l = threadIdx.x & 63;
  int row = r0 + (l & 15);
  int off = row * rowlen + kk * 32 + ((l >> 4) << 3);
  off ^= (row & 7) << 3;
  return *(const long*)(m + off);
}
DEV short8 ldsB16(const u8* m, int r0, int kk) { // LDS bf16, rowlen 512B
  int l = threadIdx.x & 63;
  int row = r0 + (l & 15);
  int off = row * 512 + kk * 64 + ((l >> 4) << 4);
  off ^= (row & 7) << 4;
  return *(const short8*)(m + off);
}
DEV void st8_256(u8* m, int row, int col, unsigned b) {
  int off = row * 256 + col; off ^= (row & 7) << 3; m[off] = (u8)b;
}
DEV void st8_64(u8* m, int row, int col, unsigned b) {
  int off = row * 64 + col; off ^= (row & 7) << 3; m[off] = (u8)b;
}
DEV void stageW(u8* dst, const u8* src, int nbytes, int rowshift) {
  for (int i = threadIdx.x * 8; i < nbytes; i += blockDim.x * 8) {
    int row = i >> rowshift;
    int off = i ^ ((row & 7) << 3);
    *(long*)(dst + off) = *(const long*)(src + i);
  }
}
DEV void stage16(u8* dst, const u8* src, int nbytes) {   // rowlen 512, bf16 tiles
  for (int i = threadIdx.x * 16; i < nbytes; i += blockDim.x * 16) {
    int row = i >> 9;
    int off = i ^ ((row & 7) << 4);
    *(f32x4*)(dst + off) = *(const f32x4*)(src + i);
  }
}

// ---------------------------------------------------------------- k_init
__global__ __launch_bounds__(256) void k_init(Params P) {
  const size_t g  = (size_t)blockIdx.x * 256 + threadIdx.x;
  const size_t gs = (size_t)gridDim.x * 256;
  // x [B,T,D] f32 -> Xbf2/Xf8 [T,B,D]
  for (size_t i = g; i < 4194304ull; i += gs) {
    size_t flat = i << 3;
    int b = (int)(flat >> 17);
    int rem = (int)(flat & 131071);
    int t = rem >> 8, d = rem & 255;
    const float* s = P.x + flat;
    f32x4 v0 = *(const f32x4*)s, v1 = *(const f32x4*)(s + 4);
    short8 o;
    o[0]=(short)f2bf(v0[0]); o[1]=(short)f2bf(v0[1]); o[2]=(short)f2bf(v0[2]); o[3]=(short)f2bf(v0[3]);
    o[4]=(short)f2bf(v1[0]); o[5]=(short)f2bf(v1[1]); o[6]=(short)f2bf(v1[2]); o[7]=(short)f2bf(v1[3]);
    size_t dst = (((size_t)t * 256 + b) << 8) + d;
    *reinterpret_cast<short8*>(P.Xbf2 + dst) = o;
    u64 p8 = 0;
    #pragma unroll
    for (int e = 0; e < 4; ++e) p8 |= (u64)f2e4m3(v0[e]) << (8 * e);
    #pragma unroll
    for (int e = 0; e < 4; ++e) p8 |= (u64)f2e4m3(v1[e]) << (8 * (e + 4));
    *(u64*)(P.Xf8 + dst) = p8;
  }
  const int gi = (int)g, gsi = (int)gs;
  for (int i = gi; i < 196608; i += gsi) {
    P.wihef8[i] = (u8)f2e4m3(P.Wih_ef[i]);  P.whhef8[i] = (u8)f2e4m3(P.Whh_ef[i]);
    P.wiheb8[i] = (u8)f2e4m3(P.Wih_eb[i]);  P.whheb8[i] = (u8)f2e4m3(P.Whh_eb[i]);
    P.whhc8[i]  = (u8)f2e4m3(P.Whh_c[i]);   P.whhg8[i]  = (u8)f2e4m3(P.Whh_g[i]);
    int r = i >> 8, c = i & 255;
    P.wihcbf[i] = f2bf(P.Wih_c[r * 320 + c]);
  }
  for (int i = gi; i < 49152; i += gsi) {
    int r = i >> 6, c = i & 63;
    P.wihcf8[i] = (u8)f2e4m3(P.Wih_c[r * 320 + 256 + c]);
    P.wihg8[i]  = (u8)f2e4m3(P.Wih_g[i]);
  }
  for (int i = gi; i < 16384; i += gsi) {
    P.wf8[i]   = (u8)f2e4m3(P.W_f[i]);
    P.wcmu8[i] = (u8)f2e4m3(P.W_cmu[i]);
    P.wclv8[i] = (u8)f2e4m3(P.W_clv[i]);
    P.wrbf[i]  = f2bf(P.W_r[i]);
  }
  for (int i = gi; i < 768; i += gsi)
    P.bfc[i] = P.bih_c[i] + (i < 512 ? P.bhh_c[i] : 0.f);
}

// ---------------------------------------------------------------- k_gx : Gxc = fp8(Wih_cx @ x^T + bfc)
// Gxc layout [t][n=768][b=256] fp8.  A = weights (M=n), B = x (N=b).
__global__ __launch_bounds__(512, 2) void k_gx(Params P) {
  extern __shared__ char smem[];
  u8* sA = (u8*)smem;            // 128 rows x 512B = 65536
  u8* sB = sA + 65536;           // 65536
  const int nc = blockIdx.x % 6;
  const int tb = blockIdx.x / 6;
  const int t = tb >> 1, bh = tb & 1;
  stage16(sA, (const u8*)(P.wihcbf + (size_t)nc * 128 * 256), 65536);
  stage16(sB, (const u8*)(P.Xbf2 + (((size_t)t * 256 + bh * 128) << 8)), 65536);
  __syncthreads();
  const int lane = threadIdx.x & 63, wid = threadIdx.x >> 6;
  const int cl = lane & 15, rq = (lane >> 4) << 2;
  const int nglob = nc * 128 + wid * 16;
  short8 Af[8];
  #pragma unroll
  for (int kk = 0; kk < 8; ++kk) Af[kk] = ldsB16(sA, wid * 16, kk);
  float bq[4];
  #pragma unroll
  for (int q = 0; q < 4; ++q) bq[q] = P.bfc[nglob + rq + q];
  #pragma unroll 1
  for (int bt = 0; bt < 8; ++bt) {
    f32x4 acc = {0.f, 0.f, 0.f, 0.f};
    #pragma unroll
    for (int kk = 0; kk < 8; ++kk)
      acc = MFMA(Af[kk], ldsB16(sB, bt * 16, kk), acc);
    #pragma unroll
    for (int q = 0; q < 4; ++q) {
      float v = acc[q] + bq[q];
      size_t a = ((size_t)t * 768 + nglob + rq + q) * 256 + bh * 128 + bt * 16 + cl;
      P.Gxc[a] = (u8)f8pk1(v);
    }
  }
}

// ---------------------------------------------------------------- k_main
// grid 48 x 512thr: blocks 0..15 ctrl+gen (16 batch rows), 16..47 encoder (dir, 16 rows)
DEV void cg_role(const Params& P, int blk, char* smem) {
  u8* sWcf = (u8*)smem;                 // 49152  [768][64] fp8
  u8* sWg  = sWcf + 49152;              // 49152  [768][64] fp8
  u8* sWhd = sWg + 49152;               // 32768  wcmu|wclv [64][256]
  u8* hc8  = sWhd + 32768;              // 2*4096
  u8* hg8  = hc8 + 8192;                // 2*4096
  u8* f8b  = hg8 + 8192;                // 2*1024
  float* sml  = (float*)(f8b + 2048);   // 16*132*4 = 8448
  float* sred = sml + 16 * 132;         // 64B

  const int lane = threadIdx.x & 63, wid = threadIdx.x >> 6;  // 8 waves
  const int cl = lane & 15, rq = (lane >> 4) << 2;
  const int b0 = blk << 4;
  const int j0 = wid << 5;              // 32 hidden cols per wave (2 colgrps)

  stageW(sWcf, P.wihcf8, 49152, 6);
  stageW(sWg,  P.wihg8,  49152, 6);
  stageW(sWhd, P.wcmu8, 16384, 8);
  stageW(sWhd + 16384, P.wclv8, 16384, 8);
  for (int i = threadIdx.x * 4; i < 18432; i += 512 * 4) *(int*)(hc8 + i) = 0;

  long wC[6][8], wG[6][8];
  #pragma unroll
  for (int cg2 = 0; cg2 < 2; ++cg2)
    #pragma unroll
    for (int g3 = 0; g3 < 3; ++g3)
      #pragma unroll
      for (int kk = 0; kk < 8; ++kk) {
        wC[cg2 * 3 + g3][kk] = glbW8(P.whhc8, g3 * 256 + j0 + cg2 * 16, kk);
        wG[cg2 * 3 + g3][kk] = glbW8(P.whhg8, g3 * 256 + j0 + cg2 * 16, kk);
      }
  float bhnC[2], bgr[2], bgz[2], bgi[2], bgh[2];
  #pragma unroll
  for (int cg2 = 0; cg2 < 2; ++cg2) {
    int j = j0 + cg2 * 16 + cl;
    bhnC[cg2] = P.bhh_c[512 + j];
    bgr[cg2] = P.bih_g[j] + P.bhh_g[j];
    bgz[cg2] = P.bih_g[256 + j] + P.bhh_g[256 + j];
    bgi[cg2] = P.bih_g[512 + j];
    bgh[cg2] = P.bhh_g[512 + j];
  }
  const float bhd = (wid >= 4 ? P.b_clv : P.b_cmu)[((wid & 3) << 4) + cl];
  const float bfac = (wid < 4) ? P.b_f[wid * 16 + cl] : 0.f;
  float hcM[2][4] = {{0,0,0,0},{0,0,0,0}};
  float hgM[2][4] = {{0,0,0,0},{0,0,0,0}};
  float klv = 0.f;
  __syncthreads();

  #pragma unroll 1
  for (int t = 0; t < 512; ++t) {
    const int cur = t & 1, prv = cur ^ 1;
    u8* hcP = hc8 + prv * 4096; u8* hcC = hc8 + cur * 4096;
    u8* hgP = hg8 + prv * 4096; u8* hgC = hg8 + cur * 4096;
    // early global loads (state-independent)
    int gxw[6];
    #pragma unroll
    for (int cg2 = 0; cg2 < 2; ++cg2)
      #pragma unroll
      for (int g3 = 0; g3 < 3; ++g3)
        gxw[cg2 * 3 + g3] = *(const int*)(P.Gxc +
            ((size_t)t * 768 + g3 * 256 + j0 + cg2 * 16 + cl) * 256 + b0 + rq);
    // ---------------- P1: controller GRU ----------------
    #pragma unroll
    for (int cg2 = 0; cg2 < 2; ++cg2) {
      f32x4 ar = {0,0,0,0}, az = {0,0,0,0}, ai = {0,0,0,0}, ah = {0,0,0,0};
      #pragma unroll
      for (int kk = 0; kk < 8; ++kk) {
        long hf = ldsA8(hcP, kk);
        ar = mfma8(hf, wC[cg2 * 3 + 0][kk], ar);
        az = mfma8(hf, wC[cg2 * 3 + 1][kk], az);
        ah = mfma8(hf, wC[cg2 * 3 + 2][kk], ah);
      }
      #pragma unroll
      for (int k2 = 0; k2 < 2; ++k2) {
        long ff = ldsW8(f8b + prv * 1024, 0, 64, k2);
        ar = mfma8(ff, ldsW8(sWcf,            j0 + cg2 * 16, 64, k2), ar);
        az = mfma8(ff, ldsW8(sWcf + 256 * 64, j0 + cg2 * 16, 64, k2), az);
        ai = mfma8(ff, ldsW8(sWcf + 512 * 64, j0 + cg2 * 16, 64, k2), ai);
      }
      unsigned gr = (unsigned)gxw[cg2 * 3 + 0], gz = (unsigned)gxw[cg2 * 3 + 1],
               gn = (unsigned)gxw[cg2 * 3 + 2];
      #pragma unroll
      for (int q = 0; q < 4; ++q) {
        float pr = ar[q] + f8tof(gr >> (8 * q));
        float pz = az[q] + f8tof(gz >> (8 * q));
        float pi = ai[q] + f8tof(gn >> (8 * q));
        float h = gru_h(pr, pz, pi, ah[q] + bhnC[cg2], hcM[cg2][q]);
        hcM[cg2][q] = h;
        st8_256(hcC, rq + q, j0 + cg2 * 16 + cl, f8pk1(h));
      }
    }
    __syncthreads();                                    // B1
    // ---------------- P2: heads -> sml ----------------
    {
      const int sel = wid >> 2, l0 = (wid & 3) << 4;
      const u8* hW = sWhd + sel * 16384;
      f32x4 am = {0,0,0,0};
      #pragma unroll
      for (int kk = 0; kk < 8; ++kk)
        am = mfma8(ldsA8(hcC, kk), ldsW8(hW, l0, 256, kk), am);
      #pragma unroll
      for (int q = 0; q < 4; ++q)
        sml[(rq + q) * 132 + sel * 64 + l0 + cl] = am[q] + bhd;
    }
    __syncthreads();                                    // B2
    // ---------------- P3: u + generator GRU ----------------
    {
      long U[2];
      const float* ep = P.eps + (((size_t)t * 256) + b0 + (lane & 15)) * 64 + ((lane >> 4) << 3);
      const float* ml = sml + (lane & 15) * 132 + ((lane >> 4) << 3);
      #pragma unroll
      for (int k2 = 0; k2 < 2; ++k2) {
        u64 uu = 0;
        #pragma unroll
        for (int e = 0; e < 8; ++e) {
          float mu = ml[k2 * 32 + e];
          float lv = ml[64 + k2 * 32 + e];
          float uv = mu + ep[k2 * 32 + e] * __expf(0.5f * lv);
          uu |= (u64)f8pk1(uv) << (8 * e);
        }
        U[k2] = (long)uu;
      }
      #pragma unroll
      for (int cg2 = 0; cg2 < 2; ++cg2) {
        f32x4 ar = {0,0,0,0}, az = {0,0,0,0}, ai = {0,0,0,0}, ah = {0,0,0,0};
        #pragma unroll
        for (int kk = 0; kk < 8; ++kk) {
          long hf = ldsA8(hgP, kk);
          ar = mfma8(hf, wG[cg2 * 3 + 0][kk], ar);
          az = mfma8(hf, wG[cg2 * 3 + 1][kk], az);
          ah = mfma8(hf, wG[cg2 * 3 + 2][kk], ah);
        }
        #pragma unroll
        for (int k2 = 0; k2 < 2; ++k2) {
          ar = mfma8(U[k2], ldsW8(sWg,            j0 + cg2 * 16, 64, k2), ar);
          az = mfma8(U[k2], ldsW8(sWg + 256 * 64, j0 + cg2 * 16, 64, k2), az);
          ai = mfma8(U[k2], ldsW8(sWg + 512 * 64, j0 + cg2 * 16, 64, k2), ai);
        }
        #pragma unroll
        for (int q = 0; q < 4; ++q) {
          float h = gru_h(ar[q] + bgr[cg2], az[q] + bgz[cg2],
                          ai[q] + bgi[cg2], ah[q] + bgh[cg2], hgM[cg2][q]);
          hgM[cg2][q] = h;
          st8_256(hgC, rq + q, j0 + cg2 * 16 + cl, f8pk1(h));
        }
      }
    }
    __syncthreads();                                    // B3
    // ---------------- P4: factors + KL ----------------
    if (wid < 4) {
      f32x4 af = {0,0,0,0};
      #pragma unroll
      for (int kk = 0; kk < 8; ++kk)
        af = mfma8(ldsA8(hgC, kk), glbW8(P.wf8, wid * 16, kk), af);
      #pragma unroll
      for (int q = 0; q < 4; ++q) {
        float f = af[q] + bfac;
        P.out[FOUT + (size_t)(b0 + rq + q) * 32768 + (size_t)t * 64 + wid * 16 + cl] = f;
        st8_64(f8b + cur * 1024, rq + q, wid * 16 + cl, f8pk1(f));
      }
    } else {
      #pragma unroll
      for (int e = 0; e < 4; ++e) {
        int p = ((wid - 4) * 64 + lane) * 4 + e;    // 0..1023
        int row = p >> 6, l = p & 63;
        float mu = sml[row * 132 + l], lv = sml[row * 132 + 64 + l];
        klv += __expf(lv) + mu * mu - 1.f - lv;
      }
    }
    __syncthreads();                                    // B4
  }
  if (wid >= 4) {
    float v = klv;
    v += __shfl_down(v, 32); v += __shfl_down(v, 16); v += __shfl_down(v, 8);
    v += __shfl_down(v, 4);  v += __shfl_down(v, 2);  v += __shfl_down(v, 1);
    if (lane == 0) sred[wid] = v;
  }
  __syncthreads();
  if (threadIdx.x == 0) P.klacc[blk] = sred[4] + sred[5] + sred[6] + sred[7];
}

DEV void enc_role(const Params& P, int dir, int b0, char* smem) {
  u8* h8 = (u8*)smem;                   // 2*4096
  const int lane = threadIdx.x & 63, wid = threadIdx.x >> 6;
  const int cl = lane & 15, rq = (lane >> 4) << 2;
  const int j0 = wid << 5;
  const u8* wih8 = dir ? P.wiheb8 : P.wihef8;
  const u8* whh8 = dir ? P.whheb8 : P.whhef8;
  const float* bih = dir ? P.bih_eb : P.bih_ef;
  const float* bhh = dir ? P.bhh_eb : P.bhh_ef;
  for (int i = threadIdx.x * 4; i < 8192; i += 512 * 4) *(int*)(h8 + i) = 0;
  long wI[6][8], wH[6][8];
  #pragma unroll
  for (int cg2 = 0; cg2 < 2; ++cg2)
    #pragma unroll
    for (int g3 = 0; g3 < 3; ++g3)
      #pragma unroll
      for (int kk = 0; kk < 8; ++kk) {
        wI[cg2 * 3 + g3][kk] = glbW8(wih8, g3 * 256 + j0 + cg2 * 16, kk);
        wH[cg2 * 3 + g3][kk] = glbW8(whh8, g3 * 256 + j0 + cg2 * 16, kk);
      }
  float ber[2], bez[2], bei[2], beh[2];
  #pragma unroll
  for (int cg2 = 0; cg2 < 2; ++cg2) {
    int j = j0 + cg2 * 16 + cl;
    ber[cg2] = bih[j] + bhh[j];
    bez[cg2] = bih[256 + j] + bhh[256 + j];
    bei[cg2] = bih[512 + j];
    beh[cg2] = bhh[512 + j];
  }
  float heM[2][4] = {{0,0,0,0},{0,0,0,0}};
  __syncthreads();
  #pragma unroll 1
  for (int i = 0; i < 512; ++i) {
    const int cur = i & 1, prv = cur ^ 1;
    const int t = dir ? (511 - i) : i;
    const u8* xrow = P.Xf8 + (((size_t)t * 256 + b0) << 8);
    u8* hP = h8 + prv * 4096; u8* hC = h8 + cur * 4096;
    #pragma unroll
    for (int cg2 = 0; cg2 < 2; ++cg2) {
      f32x4 ar = {0,0,0,0}, az = {0,0,0,0}, ai = {0,0,0,0}, ah = {0,0,0,0};
      #pragma unroll
      for (int kk = 0; kk < 8; ++kk) {
        long xf = glbW8(xrow, 0, kk);
        long hf = ldsA8(hP, kk);
        ar = mfma8(xf, wI[cg2 * 3 + 0][kk], ar);
        az = mfma8(xf, wI[cg2 * 3 + 1][kk], az);
        ai = mfma8(xf, wI[cg2 * 3 + 2][kk], ai);
        ar = mfma8(hf, wH[cg2 * 3 + 0][kk], ar);
        az = mfma8(hf, wH[cg2 * 3 + 1][kk], az);
        ah = mfma8(hf, wH[cg2 * 3 + 2][kk], ah);
      }
      #pragma unroll
      for (int q = 0; q < 4; ++q) {
        float h = gru_h(ar[q] + ber[cg2], az[q] + bez[cg2],
                        ai[q] + bei[cg2], ah[q] + beh[cg2], heM[cg2][q]);
        heM[cg2][q] = h;
        st8_256(hC, rq + q, j0 + cg2 * 16 + cl, f8pk1(h));
      }
    }
    __syncthreads();
  }
  #pragma unroll
  for (int cg2 = 0; cg2 < 2; ++cg2)
    #pragma unroll
    for (int q = 0; q < 4; ++q)
      P.henc[(size_t)(dir * 256 + b0 + rq + q) * 256 + j0 + cg2 * 16 + cl] = heM[cg2][q];
}

__global__ __launch_bounds__(512, 2) void k_main(Params P) {
  extern __shared__ char smem[];
  const int blk = blockIdx.x;
  if (blk < 16) cg_role(P, blk, smem);
  else {
    const int e = blk - 16;
    enc_role(P, e >> 4, (e & 15) << 4, smem);
  }
}

// ---------------------------------------------------------------- k_post: IC heads + rates
__global__ __launch_bounds__(256) void k_post(Params P) {
  const int blk = blockIdx.x;
  if (blk < 32) {
    __shared__ float red[4];
    float ka = 0.f;
    #pragma unroll 1
    for (int pp = 0; pp < 2; ++pp) {
      int p = blk * 512 + threadIdx.x * 2 + pp;
      int b = p >> 6, l = p & 63;
      float mu = P.b_mu0[l], lv = P.b_lv0[l];
      const float* wm = P.W_mu0 + (size_t)l * 512;
      const float* wl = P.W_lv0 + (size_t)l * 512;
      const float* h0 = P.henc + (size_t)b * 256;
      const float* h1 = P.henc + (size_t)(256 + b) * 256;
      #pragma unroll 4
      for (int k = 0; k < 256; ++k) {
        float hf = h0[k], hb = h1[k];
        mu += hf * wm[k] + hb * wm[256 + k];
        lv += hf * wl[k] + hb * wl[256 + k];
      }
      ka += __expf(lv) + mu * mu - 1.f - lv;
    }
    const int lane = threadIdx.x & 63, wid = threadIdx.x >> 6;
    ka += __shfl_down(ka, 32); ka += __shfl_down(ka, 16); ka += __shfl_down(ka, 8);
    ka += __shfl_down(ka, 4);  ka += __shfl_down(ka, 2);  ka += __shfl_down(ka, 1);
    if (lane == 0) red[wid] = ka;
    __syncthreads();
    if (threadIdx.x == 0) P.klics[blk] = red[0] + red[1] + red[2] + red[3];
  } else {
    const int lane = threadIdx.x & 63, wid = threadIdx.x >> 6;
    const int cl = lane & 15, rq = (lane >> 4) << 2;
    const int gw = (blk - 32) * 4 + wid;
    const size_t r0 = (size_t)gw << 4;
    const float* Fs = P.out + FOUT;
    short8 A0 = ldfrag_f32(Fs + r0 * 64, 64);
    short8 A1 = ldfrag_f32(Fs + r0 * 64 + 32, 64);
    #pragma unroll 1
    for (int ct = 0; ct < 16; ++ct) {
      const int d0 = ct << 4;
      const u16* W = P.wrbf + (size_t)d0 * 64;
      f32x4 a = {0,0,0,0};
      a = MFMA(A0, ldfrag(W, 64), a);
      a = MFMA(A1, ldfrag(W + 32, 64), a);
      #pragma unroll
      for (int q = 0; q < 4; ++q) {
        const size_t row = r0 + rq + q;
        P.out[row * 256 + d0 + cl] = __expf(a[q] + P.b_r[d0 + cl]);
      }
    }
  }
}

__global__ void k_final(Params P) {
  if (threadIdx.x == 0) {
    float s = 0.f, s2 = 0.f;
    for (int i = 0; i < 16; ++i) s += P.klacc[i];
    for (int i = 0; i < 32; ++i) s2 += P.klics[i];
    P.out[RATES_N]     = s2 * (0.5f / 256.f);
    P.out[RATES_N + 1] = s  * (0.5f / (256.f * 512.f));
  }
}

// ---------------------------------------------------------------- launch
extern "C" void kernel_launch(void* const* d_in, const int* in_sizes, int n_in,
                              void* d_out, int out_size, void* d_ws, size_t ws_size,
                              hipStream_t stream) {
  (void)in_sizes; (void)n_in; (void)out_size; (void)ws_size;
  Params P;
  const float* const* in = (const float* const*)d_in;
  P.x = in[0];      P.eps = in[1];
  P.Wih_ef = in[2]; P.Whh_ef = in[3]; P.bih_ef = in[4]; P.bhh_ef = in[5];
  P.Wih_eb = in[6]; P.Whh_eb = in[7]; P.bih_eb = in[8]; P.bhh_eb = in[9];
  P.W_mu0 = in[10]; P.b_mu0 = in[11]; P.W_lv0 = in[12]; P.b_lv0 = in[13];
  P.Wih_c = in[14]; P.Whh_c = in[15]; P.bih_c = in[16]; P.bhh_c = in[17];
  P.W_cmu = in[18]; P.b_cmu = in[19]; P.W_clv = in[20]; P.b_clv = in[21];
  P.Wih_g = in[22]; P.Whh_g = in[23]; P.bih_g = in[24]; P.bhh_g = in[25];
  P.W_f = in[26];   P.b_f = in[27];   P.W_r = in[28];   P.b_r = in[29];

  char* w = (char*)d_ws;
  size_t off = 0;
  auto take = [&](size_t bytes) -> char* {
    char* r = w + off;
    off = (off + bytes + 255) & ~(size_t)255;
    return r;
  };
  P.Xf8    = (u8*)take(33554432ull);
  P.Xbf2   = (u16*)take(33554432ull * 2);
  P.wihcbf = (u16*)take(196608ull * 2);
  P.bfc    = (float*)take(768ull * 4);
  P.wihef8 = (u8*)take(196608ull);
  P.whhef8 = (u8*)take(196608ull);
  P.wiheb8 = (u8*)take(196608ull);
  P.whheb8 = (u8*)take(196608ull);
  P.whhc8  = (u8*)take(196608ull);
  P.whhg8  = (u8*)take(196608ull);
  P.wihcf8 = (u8*)take(49152ull);
  P.wihg8  = (u8*)take(49152ull);
  P.wf8    = (u8*)take(16384ull);
  P.wcmu8  = (u8*)take(16384ull);
  P.wclv8  = (u8*)take(16384ull);
  P.wrbf   = (u16*)take(16384ull * 2);
  P.henc   = (float*)take(131072ull * 4);
  P.klacc  = (float*)take(64ull * 4);
  P.klics  = (float*)take(64ull * 4);
  P.Gxc    = (u8*)d_out;                 // 100,663,296 B parked in rates region
  P.out    = (float*)d_out;

  hipLaunchKernelGGL(k_init,  dim3(2048), dim3(256), 0, stream, P);
  hipLaunchKernelGGL(k_gx,    dim3(6144), dim3(512), 131072, stream, P);
  hipLaunchKernelGGL(k_main,  dim3(48),   dim3(512), 158016, stream, P);
  hipLaunchKernelGGL(k_post,  dim3(2080), dim3(256), 0, stream, P);
  hipLaunchKernelGGL(k_final, dim3(1),    dim3(64),  0, stream, P);
}

// Round 5
// 6780.891 us; speedup vs baseline: 5.0885x; 1.0595x over previous
//
#include <hip/hip_runtime.h>

typedef unsigned char u8;
typedef unsigned short u16;
typedef unsigned int u32;
typedef unsigned long long u64;
typedef short short8 __attribute__((ext_vector_type(8)));
typedef __bf16 bf16x8 __attribute__((ext_vector_type(8)));
typedef float f32x4 __attribute__((ext_vector_type(4)));
typedef float f32x2 __attribute__((ext_vector_type(2)));

#define DEV static __device__ __forceinline__

// ---------------------------------------------------------------- params
struct Params {
  const float *x, *eps;
  const float *Wih_ef, *Whh_ef, *bih_ef, *bhh_ef;
  const float *Wih_eb, *Whh_eb, *bih_eb, *bhh_eb;
  const float *W_mu0, *b_mu0, *W_lv0, *b_lv0;
  const float *Wih_c, *Whh_c, *bih_c, *bhh_c;
  const float *W_cmu, *b_cmu, *W_clv, *b_clv;
  const float *Wih_g, *Whh_g, *bih_g, *bhh_g;
  const float *W_f, *b_f, *W_r, *b_r;
  // workspace
  u8  *Xf8;                 // [T][B][256] fp8
  u16 *ebf;                 // [T][B][64] bf16 eps
  u16 *wihcbf;              // [768][256] bf16 (ctrl x-part, k_gx A)
  float *bfc;               // [768] fused bias for Gxc
  u8 *wihef8, *whhef8, *wiheb8, *whheb8;    // enc fp8 [768][256]
  u8 *whhc8, *whhg8;                        // cg fp8 [768][256]
  u8 *wihcf8, *wihg8;                       // fp8 [768][64]
  u8 *wf8;                                  // fp8 [64][256]
  u8 *wcmu8, *wclv8;                        // fp8 [64][256]
  u16 *wrbf;                                // [256][64] bf16 (k_post)
  float *cbn;               // [256]  bhh_c n-gate
  float *gb;                // [4][256] gen biases r,z,in,hn
  float *hdb;               // [128] b_cmu|b_clv
  float *fb2;               // [64]  b_f
  float *eb;                // [2][4][256] enc biases
  float *henc;              // [2*256][256] final enc h (f32)
  float *klacc;             // [16]
  float *klics;             // [32]
  u8 *Gxc;                  // [T][B][768] fp8 -> parked in d_out rates region
  float *out;
};

constexpr size_t RATES_N = 33554432ull;       // 256*512*256
constexpr size_t FOUT    = RATES_N + 2ull;    // factors_all offset in d_out

// ---------------------------------------------------------------- scalar helpers
DEV u16 f2bf(float x) {
  unsigned u = __builtin_bit_cast(unsigned, x);
  u = (u + 0x7FFFu + ((u >> 16) & 1u)) >> 16;   // RNE
  return (u16)u;
}
DEV float bf2f(u32 s) { return __builtin_bit_cast(float, s << 16); }
DEV unsigned f2e4m3(float x) {                   // manual OCP e4m3fn (RNE)
  unsigned u = __builtin_bit_cast(unsigned, x);
  unsigned s = (u >> 24) & 0x80u;
  float ax = __builtin_bit_cast(float, u & 0x7FFFFFFFu);
  if (ax > 448.f) return s | 0x7E;
  if (ax < 0.0009765625f) return s;
  if (ax < 0.015625f) {
    int m = (int)rintf(ax * 512.f);
    if (m >= 8) return s | 0x08;
    return s | (unsigned)m;
  }
  unsigned au = __builtin_bit_cast(unsigned, ax);
  int E = (int)(au >> 23) - 127;
  unsigned m = au & 0x7FFFFFu;
  unsigned r = (m + 0x7FFFFu + ((m >> 20) & 1u)) >> 20;
  if (r >= 8) { r = 0; ++E; if (E > 8) return s | 0x7E; }
  return s | ((unsigned)(E + 7) << 3) | r;
}
DEV float e4m3tof(unsigned b) {
  unsigned s = (b & 0x80u) << 24;
  unsigned e = (b >> 3) & 15u, m = b & 7u;
  float v;
  if (e) v = __builtin_bit_cast(float, ((e + 120u) << 23) | (m << 20));
  else   v = (float)m * 0.001953125f;
  return __builtin_bit_cast(float, __builtin_bit_cast(unsigned, v) | s);
}
template <bool HI>
DEV unsigned pk2fp8(float a, float b, unsigned old) {
#if __has_builtin(__builtin_amdgcn_cvt_pk_fp8_f32)
  return (unsigned)__builtin_amdgcn_cvt_pk_fp8_f32(a, b, (int)old, HI);
#else
  unsigned p = f2e4m3(a) | (f2e4m3(b) << 8);
  return HI ? ((old & 0xFFFFu) | (p << 16)) : ((old & 0xFFFF0000u) | p);
#endif
}
template <bool HI>
DEV f32x2 pkf32(unsigned w) {
#if __has_builtin(__builtin_amdgcn_cvt_pk_f32_fp8)
  return __builtin_amdgcn_cvt_pk_f32_fp8((int)w, HI);
#else
  unsigned h = HI ? (w >> 16) : w;
  f32x2 r; r[0] = e4m3tof(h & 255u); r[1] = e4m3tof((h >> 8) & 255u); return r;
#endif
}
DEV float sigm(float x) { return 1.f / (1.f + __expf(-x)); }
DEV float ftanh(float x) { float t = __expf(2.f * x); return 1.f - 2.f / (t + 1.f); }
DEV float gru_h(float pr, float pz, float pin, float phn, float hp) {
  float r = sigm(pr), z = sigm(pz);
  float n = ftanh(pin + r * phn);
  return (1.f - z) * n + z * hp;
}

// ---------------------------------------------------------------- MFMA helpers
DEV f32x4 MFMA(short8 a, short8 b, f32x4 c) {
  return __builtin_amdgcn_mfma_f32_16x16x32_bf16(
      __builtin_bit_cast(bf16x8, a), __builtin_bit_cast(bf16x8, b), c, 0, 0, 0);
}
DEV f32x4 mfma8(long a, long b, f32x4 c) {       // A=first arg (rows), B=second (cols)
  return __builtin_amdgcn_mfma_f32_16x16x32_fp8_fp8(a, b, c, 0, 0, 0);
}
DEV short8 ldfrag(const u16* p0, int stride) {
  const int l = threadIdx.x & 63;
  const u16* p = p0 + (size_t)(l & 15) * stride + ((l >> 4) << 3);
  return *reinterpret_cast<const short8*>(p);
}
DEV short8 ldfrag_f32(const float* p0, int stride) {
  const int l = threadIdx.x & 63;
  const float* p = p0 + (size_t)(l & 15) * stride + ((l >> 4) << 3);
  f32x4 a = *reinterpret_cast<const f32x4*>(p);
  f32x4 b = *reinterpret_cast<const f32x4*>(p + 4);
  short8 r;
  r[0]=(short)f2bf(a[0]); r[1]=(short)f2bf(a[1]); r[2]=(short)f2bf(a[2]); r[3]=(short)f2bf(a[3]);
  r[4]=(short)f2bf(b[0]); r[5]=(short)f2bf(b[1]); r[6]=(short)f2bf(b[2]); r[7]=(short)f2bf(b[3]);
  return r;
}
// fp8 fragment readers. k-map: k = kk*32 + (lane>>4)*8 + e (same for A and B -> cancels)
DEV long glbW8(const u8* w, int r0, int kk) {    // global, rowlen 256 (A: rows)
  int l = threadIdx.x & 63;
  return *(const long*)(w + (size_t)(r0 + (l & 15)) * 256 + kk * 32 + ((l >> 4) << 3));
}
DEV long ldsA8(const u8* m, int kk) {            // LDS state [16 rows][256], swizzled
  int l = threadIdx.x & 63;
  int row = l & 15;
  int off = row * 256 + kk * 32 + ((l >> 4) << 3);
  off ^= (row & 7) << 3;
  return *(const long*)(m + off);
}
DEV long ldsW8(const u8* m, int r0, int rowlen, int kk) {  // LDS weights, swizzled
  int l = threadIdx.x & 63;
  int row = r0 + (l & 15);
  int off = row * rowlen + kk * 32 + ((l >> 4) << 3);
  off ^= (row & 7) << 3;
  return *(const long*)(m + off);
}
DEV short8 ldsB16(const u8* m, int r0, int kk) { // LDS bf16, rowlen 512B
  int l = threadIdx.x & 63;
  int row = r0 + (l & 15);
  int off = row * 512 + kk * 64 + ((l >> 4) << 4);
  off ^= (row & 7) << 4;
  return *(const short8*)(m + off);
}
DEV void stq32(u8* m, int row, int col, unsigned v) {   // packed 4-col state write
  int off = (row * 256 + col) ^ ((row & 7) << 3);
  *(unsigned*)(m + off) = v;
}
DEV void stageW(u8* dst, const u8* src, int nbytes, int rowshift) {
  for (int i = threadIdx.x * 8; i < nbytes; i += blockDim.x * 8) {
    int row = i >> rowshift;
    int off = i ^ ((row & 7) << 3);
    *(long*)(dst + off) = *(const long*)(src + i);
  }
}
DEV void stage16(u8* dst, const u8* src, int nbytes) {   // rowlen 512, bf16 tiles
  for (int i = threadIdx.x * 16; i < nbytes; i += blockDim.x * 16) {
    int row = i >> 9;
    int off = i ^ ((row & 7) << 4);
    *(f32x4*)(dst + off) = *(const f32x4*)(src + i);
  }
}

// ---------------------------------------------------------------- k_init
__global__ __launch_bounds__(256) void k_init(Params P) {
  const size_t g  = (size_t)blockIdx.x * 256 + threadIdx.x;
  const size_t gs = (size_t)gridDim.x * 256;
  // x [B,T,D] f32 -> Xf8 [T,B,D]
  for (size_t i = g; i < 4194304ull; i += gs) {
    size_t flat = i << 3;
    int b = (int)(flat >> 17);
    int rem = (int)(flat & 131071);
    int t = rem >> 8, d = rem & 255;
    const float* s = P.x + flat;
    f32x4 v0 = *(const f32x4*)s, v1 = *(const f32x4*)(s + 4);
    u64 p8 = 0;
    #pragma unroll
    for (int e = 0; e < 4; ++e) p8 |= (u64)f2e4m3(v0[e]) << (8 * e);
    #pragma unroll
    for (int e = 0; e < 4; ++e) p8 |= (u64)f2e4m3(v1[e]) << (8 * (e + 4));
    *(u64*)(P.Xf8 + (((size_t)t * 256 + b) << 8) + d) = p8;
  }
  // eps [T,B,64] f32 -> bf16
  for (size_t i = g; i < 1048576ull; i += gs) {
    size_t flat = i << 3;
    const float* s = P.eps + flat;
    f32x4 v0 = *(const f32x4*)s, v1 = *(const f32x4*)(s + 4);
    short8 o;
    o[0]=(short)f2bf(v0[0]); o[1]=(short)f2bf(v0[1]); o[2]=(short)f2bf(v0[2]); o[3]=(short)f2bf(v0[3]);
    o[4]=(short)f2bf(v1[0]); o[5]=(short)f2bf(v1[1]); o[6]=(short)f2bf(v1[2]); o[7]=(short)f2bf(v1[3]);
    *reinterpret_cast<short8*>(P.ebf + flat) = o;
  }
  const int gi = (int)g, gsi = (int)gs;
  for (int i = gi; i < 196608; i += gsi) {
    P.wihef8[i] = (u8)f2e4m3(P.Wih_ef[i]);  P.whhef8[i] = (u8)f2e4m3(P.Whh_ef[i]);
    P.wiheb8[i] = (u8)f2e4m3(P.Wih_eb[i]);  P.whheb8[i] = (u8)f2e4m3(P.Whh_eb[i]);
    P.whhc8[i]  = (u8)f2e4m3(P.Whh_c[i]);   P.whhg8[i]  = (u8)f2e4m3(P.Whh_g[i]);
    int r = i >> 8, c = i & 255;
    P.wihcbf[i] = f2bf(P.Wih_c[r * 320 + c]);
  }
  for (int i = gi; i < 49152; i += gsi) {
    int r = i >> 6, c = i & 63;
    P.wihcf8[i] = (u8)f2e4m3(P.Wih_c[r * 320 + 256 + c]);
    P.wihg8[i]  = (u8)f2e4m3(P.Wih_g[i]);
  }
  for (int i = gi; i < 16384; i += gsi) {
    P.wf8[i]   = (u8)f2e4m3(P.W_f[i]);
    P.wcmu8[i] = (u8)f2e4m3(P.W_cmu[i]);
    P.wclv8[i] = (u8)f2e4m3(P.W_clv[i]);
    P.wrbf[i]  = f2bf(P.W_r[i]);
  }
  for (int i = gi; i < 768; i += gsi)
    P.bfc[i] = P.bih_c[i] + (i < 512 ? P.bhh_c[i] : 0.f);
  for (int i = gi; i < 256; i += gsi) {
    P.cbn[i] = P.bhh_c[512 + i];
    P.gb[i]        = P.bih_g[i] + P.bhh_g[i];
    P.gb[256 + i]  = P.bih_g[256 + i] + P.bhh_g[256 + i];
    P.gb[512 + i]  = P.bih_g[512 + i];
    P.gb[768 + i]  = P.bhh_g[512 + i];
    P.eb[i]        = P.bih_ef[i] + P.bhh_ef[i];
    P.eb[256 + i]  = P.bih_ef[256 + i] + P.bhh_ef[256 + i];
    P.eb[512 + i]  = P.bih_ef[512 + i];
    P.eb[768 + i]  = P.bhh_ef[512 + i];
    P.eb[1024 + i] = P.bih_eb[i] + P.bhh_eb[i];
    P.eb[1280 + i] = P.bih_eb[256 + i] + P.bhh_eb[256 + i];
    P.eb[1536 + i] = P.bih_eb[512 + i];
    P.eb[1792 + i] = P.bhh_eb[512 + i];
  }
  for (int i = gi; i < 128; i += gsi) P.hdb[i] = (i < 64) ? P.b_cmu[i] : P.b_clv[i - 64];
  for (int i = gi; i < 64; i += gsi)  P.fb2[i] = P.b_f[i];
}

// ---------------------------------------------------------------- k_gx : Gxc[t][b][768] = fp8(x @ Wih_cx.T + bfc)
__global__ __launch_bounds__(512, 2) void k_gx(Params P) {
  extern __shared__ char smem[];
  u8* sA = (u8*)smem;            // weights: 128 rows x 512B
  u8* sB = sA + 65536;           // x: 128 rows x 512B
  const int nc = blockIdx.x % 6;
  const int tb = blockIdx.x / 6;
  const int t = tb >> 1, bh = tb & 1;
  stage16(sA, (const u8*)(P.wihcbf + (size_t)nc * 128 * 256), 65536);
  // stage x slice [bh*128 .. +128][256] from original [B][T][D] layout, converting to bf16
  for (int i = threadIdx.x * 8; i < 32768; i += 512 * 8) {
    int r = i >> 8, c = i & 255;
    const float* s = P.x + ((size_t)(bh * 128 + r) * 512 + t) * 256 + c;
    f32x4 v0 = *(const f32x4*)s, v1 = *(const f32x4*)(s + 4);
    short8 o;
    o[0]=(short)f2bf(v0[0]); o[1]=(short)f2bf(v0[1]); o[2]=(short)f2bf(v0[2]); o[3]=(short)f2bf(v0[3]);
    o[4]=(short)f2bf(v1[0]); o[5]=(short)f2bf(v1[1]); o[6]=(short)f2bf(v1[2]); o[7]=(short)f2bf(v1[3]);
    int off = (r * 512 + c * 2) ^ ((r & 7) << 4);
    *(short8*)(sB + off) = o;
  }
  __syncthreads();
  const int lane = threadIdx.x & 63, wid = threadIdx.x >> 6;
  const int cl = lane & 15, rq = (lane >> 4) << 2;
  const int nglob = nc * 128 + wid * 16;
  short8 Af[8];
  #pragma unroll
  for (int kk = 0; kk < 8; ++kk) Af[kk] = ldsB16(sA, wid * 16, kk);
  float bq[4];
  #pragma unroll
  for (int q = 0; q < 4; ++q) bq[q] = P.bfc[nglob + rq + q];
  #pragma unroll 1
  for (int bt = 0; bt < 8; ++bt) {
    f32x4 acc = {0.f, 0.f, 0.f, 0.f};
    #pragma unroll
    for (int kk = 0; kk < 8; ++kk)
      acc = MFMA(Af[kk], ldsB16(sB, bt * 16, kk), acc);
    float v0 = acc[0] + bq[0], v1 = acc[1] + bq[1], v2 = acc[2] + bq[2], v3 = acc[3] + bq[3];
    unsigned pw = pk2fp8<false>(v0, v1, 0u); pw = pk2fp8<true>(v2, v3, pw);
    *(u32*)(P.Gxc + ((size_t)t * 256 + bh * 128 + bt * 16 + cl) * 768 + nglob + rq) = pw;
  }
}

// ---------------------------------------------------------------- k_main
DEV void cg_role(const Params& P, int blk, char* smem) {
  u8* sWcf = (u8*)smem;                 // 49152  [768][64]
  u8* sWg  = sWcf + 49152;              // 49152  [768][64]
  u8* sWhd = sWg + 49152;               // 32768  wcmu|wclv
  u8* hc8  = sWhd + 32768;              // 2*4096
  u8* hg8  = hc8 + 8192;                // 2*4096
  u8* f8b  = hg8 + 8192;                // 2*1024
  float* sml  = (float*)(f8b + 2048);   // 16*132*4
  float* sred = sml + 16 * 132;

  const int lane = threadIdx.x & 63, wid = threadIdx.x >> 6;  // 8 waves
  const int cl = lane & 15, rq = (lane >> 4) << 2;
  const int b0 = blk << 4, j0 = wid << 5;

  stageW(sWcf, P.wihcf8, 49152, 6);
  stageW(sWg,  P.wihg8,  49152, 6);
  stageW(sWhd, P.wcmu8, 16384, 8);
  stageW(sWhd + 16384, P.wclv8, 16384, 8);
  for (int i = threadIdx.x * 4; i < 18432; i += 512 * 4) *(int*)(hc8 + i) = 0;

  long wC[6][8], wG[6][8];
  #pragma unroll
  for (int cg2 = 0; cg2 < 2; ++cg2)
    #pragma unroll
    for (int g3 = 0; g3 < 3; ++g3)
      #pragma unroll
      for (int kk = 0; kk < 8; ++kk) {
        wC[cg2 * 3 + g3][kk] = glbW8(P.whhc8, g3 * 256 + j0 + cg2 * 16, kk);
        wG[cg2 * 3 + g3][kk] = glbW8(P.whhg8, g3 * 256 + j0 + cg2 * 16, kk);
      }
  f32x4 hcM[2] = {{0,0,0,0},{0,0,0,0}};
  f32x4 hgM[2] = {{0,0,0,0},{0,0,0,0}};
  float klv = 0.f;
  __syncthreads();

  #pragma unroll 1
  for (int t = 0; t < 512; ++t) {
    const int cur = t & 1, prv = cur ^ 1;
    u8 *hcP = hc8 + prv * 4096, *hcC = hc8 + cur * 4096;
    u8 *hgP = hg8 + prv * 4096, *hgC = hg8 + cur * 4096;
    // early-issue coalesced Gxc loads (one u32 = 4 consecutive j)
    u32 gx[6];
    { const u8* gp = P.Gxc + ((size_t)t * 256 + b0 + cl) * 768;
      #pragma unroll
      for (int cg2 = 0; cg2 < 2; ++cg2)
        #pragma unroll
        for (int g3 = 0; g3 < 3; ++g3)
          gx[cg2 * 3 + g3] = *(const u32*)(gp + g3 * 256 + j0 + cg2 * 16 + rq);
    }
    // ---------------- P1: controller GRU ----------------
    long hf[8];
    #pragma unroll
    for (int kk = 0; kk < 8; ++kk) hf[kk] = ldsA8(hcP, kk);
    long ff0 = ldsW8(f8b + prv * 1024, 0, 64, 0);
    long ff1 = ldsW8(f8b + prv * 1024, 0, 64, 1);
    #pragma unroll
    for (int cg2 = 0; cg2 < 2; ++cg2) {
      const int jrow = j0 + cg2 * 16;
      f32x4 ar = {0,0,0,0}, az = {0,0,0,0}, ai = {0,0,0,0}, ah = {0,0,0,0};
      #pragma unroll
      for (int kk = 0; kk < 8; ++kk) {
        ar = mfma8(wC[cg2 * 3 + 0][kk], hf[kk], ar);
        az = mfma8(wC[cg2 * 3 + 1][kk], hf[kk], az);
        ah = mfma8(wC[cg2 * 3 + 2][kk], hf[kk], ah);
      }
      ar = mfma8(ldsW8(sWcf,            jrow, 64, 0), ff0, ar);
      ar = mfma8(ldsW8(sWcf,            jrow, 64, 1), ff1, ar);
      az = mfma8(ldsW8(sWcf + 256 * 64, jrow, 64, 0), ff0, az);
      az = mfma8(ldsW8(sWcf + 256 * 64, jrow, 64, 1), ff1, az);
      ai = mfma8(ldsW8(sWcf + 512 * 64, jrow, 64, 0), ff0, ai);
      ai = mfma8(ldsW8(sWcf + 512 * 64, jrow, 64, 1), ff1, ai);
      f32x4 bn = *(const f32x4*)(P.cbn + jrow + rq);
      f32x2 rlo = pkf32<false>(gx[cg2*3+0]), rhi = pkf32<true>(gx[cg2*3+0]);
      f32x2 zlo = pkf32<false>(gx[cg2*3+1]), zhi = pkf32<true>(gx[cg2*3+1]);
      f32x2 nlo = pkf32<false>(gx[cg2*3+2]), nhi = pkf32<true>(gx[cg2*3+2]);
      float h0 = gru_h(ar[0]+rlo[0], az[0]+zlo[0], ai[0]+nlo[0], ah[0]+bn[0], hcM[cg2][0]);
      float h1 = gru_h(ar[1]+rlo[1], az[1]+zlo[1], ai[1]+nlo[1], ah[1]+bn[1], hcM[cg2][1]);
      float h2 = gru_h(ar[2]+rhi[0], az[2]+zhi[0], ai[2]+nhi[0], ah[2]+bn[2], hcM[cg2][2]);
      float h3 = gru_h(ar[3]+rhi[1], az[3]+zhi[1], ai[3]+nhi[1], ah[3]+bn[3], hcM[cg2][3]);
      hcM[cg2][0] = h0; hcM[cg2][1] = h1; hcM[cg2][2] = h2; hcM[cg2][3] = h3;
      unsigned pw = pk2fp8<false>(h0, h1, 0u); pw = pk2fp8<true>(h2, h3, pw);
      stq32(hcC, cl, jrow + rq, pw);
    }
    __syncthreads();                                    // B1
    // early-issue eps (bf16) -- FULL 8 elements per half (16B short8 loads)
    const u16* ep16 = P.ebf + ((size_t)t * 256 + b0 + cl) * 64 + ((lane >> 4) << 3);
    short8 ee0 = *(const short8*)(ep16);
    short8 ee1 = *(const short8*)(ep16 + 32);
    // ---------------- P2: heads -> sml ----------------
    { const int sel = wid >> 2, l0 = (wid & 3) << 4;
      const u8* hW = sWhd + sel * 16384;
      f32x4 am = {0,0,0,0};
      #pragma unroll
      for (int kk = 0; kk < 8; ++kk)
        am = mfma8(ldsW8(hW, l0, 256, kk), ldsA8(hcC, kk), am);
      f32x4 hb = *(const f32x4*)(P.hdb + sel * 64 + l0 + rq);
      am += hb;
      *(f32x4*)(sml + cl * 132 + sel * 64 + l0 + rq) = am;
    }
    __syncthreads();                                    // B2
    // ---------------- P3: u + generator GRU ----------------
    long U[2];
    { const float* ml = sml + cl * 132;
      const int kh = (lane >> 4) << 3;
      #pragma unroll
      for (int k2 = 0; k2 < 2; ++k2) {
        f32x4 mu0 = *(const f32x4*)(ml + k2 * 32 + kh);
        f32x4 mu1 = *(const f32x4*)(ml + k2 * 32 + kh + 4);
        f32x4 lv0 = *(const f32x4*)(ml + 64 + k2 * 32 + kh);
        f32x4 lv1 = *(const f32x4*)(ml + 64 + k2 * 32 + kh + 4);
        short8 ev = k2 ? ee1 : ee0;
        float uu[8];
        #pragma unroll
        for (int e = 0; e < 4; ++e) {
          float epv = bf2f((u32)(u16)ev[e]);
          uu[e] = mu0[e] + epv * __expf(0.5f * lv0[e]);
        }
        #pragma unroll
        for (int e = 0; e < 4; ++e) {
          float epv = bf2f((u32)(u16)ev[4 + e]);
          uu[4 + e] = mu1[e] + epv * __expf(0.5f * lv1[e]);
        }
        unsigned pa = pk2fp8<false>(uu[0], uu[1], 0u); pa = pk2fp8<true>(uu[2], uu[3], pa);
        unsigned pb = pk2fp8<false>(uu[4], uu[5], 0u); pb = pk2fp8<true>(uu[6], uu[7], pb);
        U[k2] = (long)(((u64)pb << 32) | (u64)pa);
      }
    }
    long hg[8];
    #pragma unroll
    for (int kk = 0; kk < 8; ++kk) hg[kk] = ldsA8(hgP, kk);
    #pragma unroll
    for (int cg2 = 0; cg2 < 2; ++cg2) {
      const int jrow = j0 + cg2 * 16;
      f32x4 gr = {0,0,0,0}, gz = {0,0,0,0}, gi = {0,0,0,0}, gh = {0,0,0,0};
      #pragma unroll
      for (int kk = 0; kk < 8; ++kk) {
        gr = mfma8(wG[cg2 * 3 + 0][kk], hg[kk], gr);
        gz = mfma8(wG[cg2 * 3 + 1][kk], hg[kk], gz);
        gh = mfma8(wG[cg2 * 3 + 2][kk], hg[kk], gh);
      }
      gr = mfma8(ldsW8(sWg,            jrow, 64, 0), U[0], gr);
      gr = mfma8(ldsW8(sWg,            jrow, 64, 1), U[1], gr);
      gz = mfma8(ldsW8(sWg + 256 * 64, jrow, 64, 0), U[0], gz);
      gz = mfma8(ldsW8(sWg + 256 * 64, jrow, 64, 1), U[1], gz);
      gi = mfma8(ldsW8(sWg + 512 * 64, jrow, 64, 0), U[0], gi);
      gi = mfma8(ldsW8(sWg + 512 * 64, jrow, 64, 1), U[1], gi);
      f32x4 br  = *(const f32x4*)(P.gb +           jrow + rq);
      f32x4 bz  = *(const f32x4*)(P.gb + 256 +     jrow + rq);
      f32x4 bi  = *(const f32x4*)(P.gb + 512 +     jrow + rq);
      f32x4 bh2 = *(const f32x4*)(P.gb + 768 +     jrow + rq);
      float h0 = gru_h(gr[0]+br[0], gz[0]+bz[0], gi[0]+bi[0], gh[0]+bh2[0], hgM[cg2][0]);
      float h1 = gru_h(gr[1]+br[1], gz[1]+bz[1], gi[1]+bi[1], gh[1]+bh2[1], hgM[cg2][1]);
      float h2 = gru_h(gr[2]+br[2], gz[2]+bz[2], gi[2]+bi[2], gh[2]+bh2[2], hgM[cg2][2]);
      float h3 = gru_h(gr[3]+br[3], gz[3]+bz[3], gi[3]+bi[3], gh[3]+bh2[3], hgM[cg2][3]);
      hgM[cg2][0] = h0; hgM[cg2][1] = h1; hgM[cg2][2] = h2; hgM[cg2][3] = h3;
      unsigned pw = pk2fp8<false>(h0, h1, 0u); pw = pk2fp8<true>(h2, h3, pw);
      stq32(hgC, cl, jrow + rq, pw);
    }
    __syncthreads();                                    // B3
    // ---------------- P4: factors + KL ----------------
    if (wid < 4) {
      f32x4 af = {0,0,0,0};
      #pragma unroll
      for (int kk = 0; kk < 8; ++kk)
        af = mfma8(glbW8(P.wf8, wid * 16, kk), ldsA8(hgC, kk), af);
      f32x4 fb = *(const f32x4*)(P.fb2 + wid * 16 + rq);
      af += fb;
      float* fo = P.out + FOUT + (size_t)(b0 + cl) * 32768 + (size_t)t * 64 + wid * 16 + rq;
      f32x2 lo = {af[0], af[1]}, hi2 = {af[2], af[3]};
      *(f32x2*)fo = lo;
      *(f32x2*)(fo + 2) = hi2;
      unsigned pw = pk2fp8<false>(af[0], af[1], 0u); pw = pk2fp8<true>(af[2], af[3], pw);
      int off = (cl * 64 + wid * 16 + rq) ^ ((cl & 7) << 3);
      *(unsigned*)(f8b + cur * 1024 + off) = pw;
    } else {
      #pragma unroll
      for (int e = 0; e < 4; ++e) {
        int p = ((wid - 4) * 64 + lane) * 4 + e;
        int row = p >> 6, l = p & 63;
        float mu = sml[row * 132 + l], lv = sml[row * 132 + 64 + l];
        klv += __expf(lv) + mu * mu - 1.f - lv;
      }
    }
    __syncthreads();                                    // B4
  }
  if (wid >= 4) {
    float v = klv;
    v += __shfl_down(v, 32); v += __shfl_down(v, 16); v += __shfl_down(v, 8);
    v += __shfl_down(v, 4);  v += __shfl_down(v, 2);  v += __shfl_down(v, 1);
    if (lane == 0) sred[wid] = v;
  }
  __syncthreads();
  if (threadIdx.x == 0) P.klacc[blk] = sred[4] + sred[5] + sred[6] + sred[7];
}

DEV void enc_role(const Params& P, int dir, int b0, char* smem) {
  u8* h8 = (u8*)smem;                   // 2*4096 state
  u8* sx = h8 + 8192;                   // 2*4096 x tile double buffer
  const int lane = threadIdx.x & 63, wid = threadIdx.x >> 6;
  const int cl = lane & 15, rq = (lane >> 4) << 2;
  const int j0 = wid << 5;
  const u8* wih8 = dir ? P.wiheb8 : P.wihef8;
  const u8* whh8 = dir ? P.whheb8 : P.whhef8;
  const float* ebt = P.eb + dir * 1024;
  for (int i = threadIdx.x * 4; i < 8192; i += 512 * 4) *(int*)(h8 + i) = 0;
  long wI[6][8], wH[6][8];
  #pragma unroll
  for (int cg2 = 0; cg2 < 2; ++cg2)
    #pragma unroll
    for (int g3 = 0; g3 < 3; ++g3)
      #pragma unroll
      for (int kk = 0; kk < 8; ++kk) {
        wI[cg2 * 3 + g3][kk] = glbW8(wih8, g3 * 256 + j0 + cg2 * 16, kk);
        wH[cg2 * 3 + g3][kk] = glbW8(whh8, g3 * 256 + j0 + cg2 * 16, kk);
      }
  f32x4 heM[2] = {{0,0,0,0},{0,0,0,0}};
  // prologue: stage first x tile (swizzled-source, linear LDS)
  const int t0 = dir ? 511 : 0;
  const int dd = threadIdx.x * 8;
  const int gg = dd ^ (((dd >> 8) & 7) << 3);
  *(u64*)(sx + dd) = *(const u64*)(P.Xf8 + (((size_t)t0 * 256 + b0) << 8) + gg);
  __syncthreads();

  #pragma unroll 1
  for (int i = 0; i < 512; ++i) {
    const int cur = i & 1, prv = cur ^ 1;
    const int t = dir ? (511 - i) : i;
    u8 *hP = h8 + prv * 4096, *hC = h8 + cur * 4096;
    const u8* sxc = sx + cur * 4096;
    // early-issue prefetch of next x tile
    u64 xpre = 0;
    if (i < 511) {
      int tn = dir ? (t - 1) : (t + 1);
      xpre = *(const u64*)(P.Xf8 + (((size_t)tn * 256 + b0) << 8) + gg);
    }
    long hp[8], xf[8];
    #pragma unroll
    for (int kk = 0; kk < 8; ++kk) { hp[kk] = ldsA8(hP, kk); xf[kk] = ldsA8(sxc, kk); }
    #pragma unroll
    for (int cg2 = 0; cg2 < 2; ++cg2) {
      const int jrow = j0 + cg2 * 16;
      f32x4 er = {0,0,0,0}, ez = {0,0,0,0}, ei = {0,0,0,0}, eh = {0,0,0,0};
      #pragma unroll
      for (int kk = 0; kk < 8; ++kk) {
        er = mfma8(wH[cg2 * 3 + 0][kk], hp[kk], er);
        ez = mfma8(wH[cg2 * 3 + 1][kk], hp[kk], ez);
        eh = mfma8(wH[cg2 * 3 + 2][kk], hp[kk], eh);
      }
      #pragma unroll
      for (int kk = 0; kk < 8; ++kk) {
        er = mfma8(wI[cg2 * 3 + 0][kk], xf[kk], er);
        ez = mfma8(wI[cg2 * 3 + 1][kk], xf[kk], ez);
        ei = mfma8(wI[cg2 * 3 + 2][kk], xf[kk], ei);
      }
      f32x4 br  = *(const f32x4*)(ebt +        jrow + rq);
      f32x4 bz  = *(const f32x4*)(ebt + 256 +  jrow + rq);
      f32x4 bi  = *(const f32x4*)(ebt + 512 +  jrow + rq);
      f32x4 bh2 = *(const f32x4*)(ebt + 768 +  jrow + rq);
      float h0 = gru_h(er[0]+br[0], ez[0]+bz[0], ei[0]+bi[0], eh[0]+bh2[0], heM[cg2][0]);
      float h1 = gru_h(er[1]+br[1], ez[1]+bz[1], ei[1]+bi[1], eh[1]+bh2[1], heM[cg2][1]);
      float h2 = gru_h(er[2]+br[2], ez[2]+bz[2], ei[2]+bi[2], eh[2]+bh2[2], heM[cg2][2]);
      float h3 = gru_h(er[3]+br[3], ez[3]+bz[3], ei[3]+bi[3], eh[3]+bh2[3], heM[cg2][3]);
      heM[cg2][0] = h0; heM[cg2][1] = h1; heM[cg2][2] = h2; heM[cg2][3] = h3;
      unsigned pw = pk2fp8<false>(h0, h1, 0u); pw = pk2fp8<true>(h2, h3, pw);
      stq32(hC, cl, jrow + rq, pw);
    }
    if (i < 511) *(u64*)(sx + prv * 4096 + dd) = xpre;   // prv buffer = next step's cur
    __syncthreads();
  }
  #pragma unroll
  for (int cg2 = 0; cg2 < 2; ++cg2)
    *(f32x4*)(P.henc + (size_t)(dir * 256 + b0 + cl) * 256 + j0 + cg2 * 16 + rq) = heM[cg2];
}

__global__ __launch_bounds__(512, 2) void k_main(Params P) {
  extern __shared__ char smem[];
  const int blk = blockIdx.x;
  if (blk < 16) cg_role(P, blk, smem);
  else {
    const int e = blk - 16;
    enc_role(P, e >> 4, (e & 15) << 4, smem);
  }
}

// ---------------------------------------------------------------- k_post: IC heads + rates
__global__ __launch_bounds__(256) void k_post(Params P) {
  const int blk = blockIdx.x;
  if (blk < 32) {
    __shared__ float red[4];
    float ka = 0.f;
    #pragma unroll 1
    for (int pp = 0; pp < 2; ++pp) {
      int p = blk * 512 + threadIdx.x * 2 + pp;
      int b = p >> 6, l = p & 63;
      float mu = P.b_mu0[l], lv = P.b_lv0[l];
      const float* wm = P.W_mu0 + (size_t)l * 512;
      const float* wl = P.W_lv0 + (size_t)l * 512;
      const float* h0 = P.henc + (size_t)b * 256;
      const float* h1 = P.henc + (size_t)(256 + b) * 256;
      #pragma unroll 4
      for (int k = 0; k < 256; ++k) {
        float hf = h0[k], hb = h1[k];
        mu += hf * wm[k] + hb * wm[256 + k];
        lv += hf * wl[k] + hb * wl[256 + k];
      }
      ka += __expf(lv) + mu * mu - 1.f - lv;
    }
    const int lane = threadIdx.x & 63, wid = threadIdx.x >> 6;
    ka += __shfl_down(ka, 32); ka += __shfl_down(ka, 16); ka += __shfl_down(ka, 8);
    ka += __shfl_down(ka, 4);  ka += __shfl_down(ka, 2);  ka += __shfl_down(ka, 1);
    if (lane == 0) red[wid] = ka;
    __syncthreads();
    if (threadIdx.x == 0) P.klics[blk] = red[0] + red[1] + red[2] + red[3];
  } else {
    const int lane = threadIdx.x & 63, wid = threadIdx.x >> 6;
    const int cl = lane & 15, rq = (lane >> 4) << 2;
    const int gw = (blk - 32) * 4 + wid;
    const size_t r0 = (size_t)gw << 4;                 // 16 (b,t) rows per wave
    const float* Fs = P.out + FOUT;
    short8 F0 = ldfrag_f32(Fs + r0 * 64, 64);
    short8 F1 = ldfrag_f32(Fs + r0 * 64 + 32, 64);
    #pragma unroll 1
    for (int ct = 0; ct < 16; ++ct) {
      const int d0 = ct << 4;
      const u16* W = P.wrbf + (size_t)d0 * 64;
      f32x4 a = {0,0,0,0};
      a = MFMA(ldfrag(W, 64), F0, a);
      a = MFMA(ldfrag(W + 32, 64), F1, a);
      f32x4 rb = *(const f32x4*)(P.b_r + d0 + rq);
      f32x4 o;
      o[0] = __expf(a[0] + rb[0]); o[1] = __expf(a[1] + rb[1]);
      o[2] = __expf(a[2] + rb[2]); o[3] = __expf(a[3] + rb[3]);
      *(f32x4*)(P.out + (r0 + cl) * 256 + d0 + rq) = o;
    }
  }
}

__global__ void k_final(Params P) {
  if (threadIdx.x == 0) {
    float s = 0.f, s2 = 0.f;
    for (int i = 0; i < 16; ++i) s += P.klacc[i];
    for (int i = 0; i < 32; ++i) s2 += P.klics[i];
    P.out[RATES_N]     = s2 * (0.5f / 256.f);
    P.out[RATES_N + 1] = s  * (0.5f / (256.f * 512.f));
  }
}

// ---------------------------------------------------------------- launch
extern "C" void kernel_launch(void* const* d_in, const int* in_sizes, int n_in,
                              void* d_out, int out_size, void* d_ws, size_t ws_size,
                              hipStream_t stream) {
  (void)in_sizes; (void)n_in; (void)out_size; (void)ws_size;
  Params P;
  const float* const* in = (const float* const*)d_in;
  P.x = in[0];      P.eps = in[1];
  P.Wih_ef = in[2]; P.Whh_ef = in[3]; P.bih_ef = in[4]; P.bhh_ef = in[5];
  P.Wih_eb = in[6]; P.Whh_eb = in[7]; P.bih_eb = in[8]; P.bhh_eb = in[9];
  P.W_mu0 = in[10]; P.b_mu0 = in[11]; P.W_lv0 = in[12]; P.b_lv0 = in[13];
  P.Wih_c = in[14]; P.Whh_c = in[15]; P.bih_c = in[16]; P.bhh_c = in[17];
  P.W_cmu = in[18]; P.b_cmu = in[19]; P.W_clv = in[20]; P.b_clv = in[21];
  P.Wih_g = in[22]; P.Whh_g = in[23]; P.bih_g = in[24]; P.bhh_g = in[25];
  P.W_f = in[26];   P.b_f = in[27];   P.W_r = in[28];   P.b_r = in[29];

  char* w = (char*)d_ws;
  size_t off = 0;
  auto take = [&](size_t bytes) -> char* {
    char* r = w + off;
    off = (off + bytes + 255) & ~(size_t)255;
    return r;
  };
  P.Xf8    = (u8*)take(33554432ull);
  P.ebf    = (u16*)take(16777216ull * 2);
  P.wihcbf = (u16*)take(196608ull * 2);
  P.bfc    = (float*)take(768ull * 4);
  P.wihef8 = (u8*)take(196608ull);
  P.whhef8 = (u8*)take(196608ull);
  P.wiheb8 = (u8*)take(196608ull);
  P.whheb8 = (u8*)take(196608ull);
  P.whhc8  = (u8*)take(196608ull);
  P.whhg8  = (u8*)take(196608ull);
  P.wihcf8 = (u8*)take(49152ull);
  P.wihg8  = (u8*)take(49152ull);
  P.wf8    = (u8*)take(16384ull);
  P.wcmu8  = (u8*)take(16384ull);
  P.wclv8  = (u8*)take(16384ull);
  P.wrbf   = (u16*)take(16384ull * 2);
  P.cbn    = (float*)take(256ull * 4);
  P.gb     = (float*)take(1024ull * 4);
  P.hdb    = (float*)take(128ull * 4);
  P.fb2    = (float*)take(64ull * 4);
  P.eb     = (float*)take(2048ull * 4);
  P.henc   = (float*)take(131072ull * 4);
  P.klacc  = (float*)take(64ull * 4);
  P.klics  = (float*)take(64ull * 4);
  P.Gxc    = (u8*)d_out;                 // [T][B][768] parked in rates region
  P.out    = (float*)d_out;

  hipLaunchKernelGGL(k_init,  dim3(2048), dim3(256), 0, stream, P);
  hipLaunchKernelGGL(k_gx,    dim3(6144), dim3(512), 131072, stream, P);
  hipLaunchKernelGGL(k_main,  dim3(48),   dim3(512), 158016, stream, P);
  hipLaunchKernelGGL(k_post,  dim3(2080), dim3(256), 0, stream, P);
  hipLaunchKernelGGL(k_final, dim3(1),    dim3(64),  0, stream, P);
}